// Round 1
// 11707.179 us; speedup vs baseline: 5.5998x; 5.5998x over previous
//
#include <hip/hip_runtime.h>
#include <math.h>

typedef unsigned short ushort_t;

#define SLABF (512 * 576)   /* floats per (b,t) scratch slab */

__device__ __forceinline__ float bf2f(ushort_t u) {
    union { unsigned int i; float f; } v;
    v.i = ((unsigned int)u) << 16;
    return v.f;
}
__device__ __forceinline__ ushort_t f2bf(float f) {
    union { float f; unsigned int i; } v;
    v.f = f;
    unsigned int r = v.i + 0x7FFFu + ((v.i >> 16) & 1u);
    return (ushort_t)(r >> 16);
}

// Read input element i from a buffer whose true dtype is selected by flag.
__device__ __forceinline__ float in_read(const void* p, size_t i, int is_f32) {
    if (is_f32) return ((const float*)p)[i];
    return bf2f(((const ushort_t*)p)[i]);
}

// ---------------------------------------------------------------------------
// Dtype probe (unchanged): read first 4096 halves of wq as bf16. fp32 data
// read as bf16 shows wild exponents in ~40% of even halves.
// ---------------------------------------------------------------------------
__global__ void detect_dtype(const ushort_t* wq_h, int* flag) {
    __shared__ int cnt;
    if (threadIdx.x == 0) cnt = 0;
    __syncthreads();
    int local = 0;
    for (int i = threadIdx.x; i < 4096; i += 256) {
        float v = bf2f(wq_h[i]);
        if (!(fabsf(v) < 1e6f)) local++;
    }
    atomicAdd(&cnt, local);
    __syncthreads();
    if (threadIdx.x == 0) flag[0] = (cnt > 10) ? 1 : 0;
}

// ---------------------------------------------------------------------------
// Fused QKV projection, tiled GEMM, batched over (b,t) chunk.
// Out[mode][btl][o][p] = sum_c W[o][c] * (x[b][c][t][p] + pos[c][t]) + bias[o]
// Tile: 64 o x 64 p, BK=16. 256 threads, 4x4 microtile each.
// grid: (9 p-tiles, 8 o-tiles, nbt*3) with z = btl*3 + mode.
// ---------------------------------------------------------------------------
__global__ __launch_bounds__(256)
void proj_qkv_gemm(const void* __restrict__ x, const void* __restrict__ pos,
                   const void* __restrict__ w0, const void* __restrict__ b0,
                   const void* __restrict__ w1, const void* __restrict__ b1,
                   const void* __restrict__ w2, const void* __restrict__ b2,
                   float* __restrict__ qs, float* __restrict__ ks, float* __restrict__ vs,
                   const int* __restrict__ flag, int bt_base)
{
    const int is_f32 = flag[0];
    const int z = blockIdx.z;
    const int btl = z / 3;
    const int mode = z - btl * 3;
    const int bt = bt_base + btl;
    const int b = bt >> 4, t = bt & 15;

    const void* W; const void* bias; float* out;
    if (mode == 0)      { W = w0; bias = b0; out = qs; }
    else if (mode == 1) { W = w1; bias = b1; out = ks; }
    else                { W = w2; bias = b2; out = vs; }
    out += (size_t)btl * SLABF;

    const int o0 = blockIdx.y * 64;
    const int p0 = blockIdx.x * 64;
    const int tid = threadIdx.x;
    const int tx = tid & 15;   // p microtile index
    const int ty = tid >> 4;   // o microtile index

    __shared__ float  As[16][68];   // [c][o], padded: <=2-way bank alias
    __shared__ float4 Bs[16][17];   // [c][p/4], padded

    float acc[4][4];
    #pragma unroll
    for (int r = 0; r < 4; ++r) {
        float bb = in_read(bias, (size_t)(o0 + ty * 4 + r), is_f32);
        #pragma unroll
        for (int j = 0; j < 4; ++j) acc[r][j] = bb;
    }

    // W-tile: 64 o x 16 c, 4 consecutive c per thread
    const int wo_l = tid >> 2;
    const int wc_l = (tid & 3) * 4;
    // X-tile: 16 c x 64 p, 4 consecutive p per thread
    const int xc_l = ty;
    const int xp_l = tx * 4;

    for (int c0 = 0; c0 < 512; c0 += 16) {
        {
            size_t wbase = (size_t)(o0 + wo_l) * 512 + (size_t)(c0 + wc_l);
            #pragma unroll
            for (int i = 0; i < 4; ++i)
                As[wc_l + i][wo_l] = in_read(W, wbase + i, is_f32);
        }
        {
            float pv = in_read(pos, (size_t)(c0 + xc_l) * 16 + t, is_f32);
            size_t xbase = ((size_t)(b * 512 + c0 + xc_l) * 16 + t) * 576 + p0 + xp_l;
            float4 xv;
            xv.x = in_read(x, xbase + 0, is_f32) + pv;
            xv.y = in_read(x, xbase + 1, is_f32) + pv;
            xv.z = in_read(x, xbase + 2, is_f32) + pv;
            xv.w = in_read(x, xbase + 3, is_f32) + pv;
            Bs[xc_l][tx] = xv;
        }
        __syncthreads();
        #pragma unroll
        for (int kk = 0; kk < 16; ++kk) {
            float4 bv = Bs[kk][tx];
            #pragma unroll
            for (int r = 0; r < 4; ++r) {
                float a = As[kk][ty * 4 + r];
                acc[r][0] += a * bv.x;
                acc[r][1] += a * bv.y;
                acc[r][2] += a * bv.z;
                acc[r][3] += a * bv.w;
            }
        }
        __syncthreads();
    }

    #pragma unroll
    for (int r = 0; r < 4; ++r) {
        float4 st;
        st.x = acc[r][0]; st.y = acc[r][1]; st.z = acc[r][2]; st.w = acc[r][3];
        *(float4*)&out[(size_t)(o0 + ty * 4 + r) * 576 + p0 + tx * 4] = st;
    }
}

// ---------------------------------------------------------------------------
// Attention, batched over (b,t) chunk: one thread per (h, query).
// grid (3, 8, nbt), block 192. AO overwrites Q in place (thread reads its own
// column fully before writing it; column sets across threads are disjoint).
// ---------------------------------------------------------------------------
__global__ __launch_bounds__(192)
void attn_batched(float* __restrict__ qs, const float* __restrict__ ks,
                  const float* __restrict__ vs)
{
    const size_t slab = (size_t)blockIdx.z * SLABF;
    const int h = blockIdx.y;
    const int q = blockIdx.x * 192 + threadIdx.x;   // 0..575
    const size_t base = slab + (size_t)(h * 64) * 576;

    float Qr[64];
    #pragma unroll
    for (int d = 0; d < 64; ++d)
        Qr[d] = qs[base + (size_t)d * 576 + q] * 0.125f;

    float O[64];
    #pragma unroll
    for (int d = 0; d < 64; ++d) O[d] = 0.f;
    float l = 0.f;

    for (int kv = 0; kv < 576; ++kv) {
        float s = 0.f;
        #pragma unroll
        for (int d = 0; d < 64; ++d)
            s += Qr[d] * ks[base + (size_t)d * 576 + kv];
        float e = __expf(s);
        l += e;
        #pragma unroll
        for (int d = 0; d < 64; ++d)
            O[d] += e * vs[base + (size_t)d * 576 + kv];
    }

    float inv = 1.f / l;
    #pragma unroll
    for (int d = 0; d < 64; ++d)
        qs[base + (size_t)d * 576 + q] = O[d] * inv;
}

// ---------------------------------------------------------------------------
// Output projection, tiled GEMM, batched over (b,t) chunk.
// d_out[b][o][t][p] = sum_c wo[o][c] * AO[c][p] + bo[o]
// grid (9, 8, nbt), block 256.
// ---------------------------------------------------------------------------
__global__ __launch_bounds__(256)
void proj_out_gemm(const float* __restrict__ ao,
                   const void* __restrict__ wo, const void* __restrict__ bo,
                   void* __restrict__ out, const int* __restrict__ flag, int bt_base)
{
    const int is_f32 = flag[0];
    const int btl = blockIdx.z;
    const int bt = bt_base + btl;
    const int b = bt >> 4, t = bt & 15;
    const float* A = ao + (size_t)btl * SLABF;

    const int o0 = blockIdx.y * 64;
    const int p0 = blockIdx.x * 64;
    const int tid = threadIdx.x;
    const int tx = tid & 15;
    const int ty = tid >> 4;

    __shared__ float  As[16][68];
    __shared__ float4 Bs[16][17];

    float acc[4][4];
    #pragma unroll
    for (int r = 0; r < 4; ++r) {
        float bb = in_read(bo, (size_t)(o0 + ty * 4 + r), is_f32);
        #pragma unroll
        for (int j = 0; j < 4; ++j) acc[r][j] = bb;
    }

    const int wo_l = tid >> 2;
    const int wc_l = (tid & 3) * 4;
    const int xc_l = ty;
    const int xp_l = tx * 4;

    for (int c0 = 0; c0 < 512; c0 += 16) {
        {
            size_t wbase = (size_t)(o0 + wo_l) * 512 + (size_t)(c0 + wc_l);
            #pragma unroll
            for (int i = 0; i < 4; ++i)
                As[wc_l + i][wo_l] = in_read(wo, wbase + i, is_f32);
        }
        Bs[xc_l][tx] = *(const float4*)&A[(size_t)(c0 + xc_l) * 576 + p0 + xp_l];
        __syncthreads();
        #pragma unroll
        for (int kk = 0; kk < 16; ++kk) {
            float4 bv = Bs[kk][tx];
            #pragma unroll
            for (int r = 0; r < 4; ++r) {
                float a = As[kk][ty * 4 + r];
                acc[r][0] += a * bv.x;
                acc[r][1] += a * bv.y;
                acc[r][2] += a * bv.z;
                acc[r][3] += a * bv.w;
            }
        }
        __syncthreads();
    }

    #pragma unroll
    for (int r = 0; r < 4; ++r) {
        const int o = o0 + ty * 4 + r;
        const size_t addr = ((size_t)(b * 512 + o) * 16 + t) * 576 + p0 + tx * 4;
        if (is_f32) {
            float4 st;
            st.x = acc[r][0]; st.y = acc[r][1]; st.z = acc[r][2]; st.w = acc[r][3];
            *(float4*)((float*)out + addr) = st;
        } else {
            unsigned int lo = (unsigned int)f2bf(acc[r][0]) |
                              ((unsigned int)f2bf(acc[r][1]) << 16);
            unsigned int hi = (unsigned int)f2bf(acc[r][2]) |
                              ((unsigned int)f2bf(acc[r][3]) << 16);
            uint2 st; st.x = lo; st.y = hi;
            *(uint2*)((ushort_t*)out + addr) = st;   // 8B aligned: addr*2 % 8 == 0
        }
    }
}

extern "C" void kernel_launch(void* const* d_in, const int* in_sizes, int n_in,
                              void* d_out, int out_size, void* d_ws, size_t ws_size,
                              hipStream_t stream)
{
    (void)in_sizes; (void)n_in; (void)out_size;
    const void* x   = d_in[0];
    const void* wq  = d_in[1];
    const void* bq  = d_in[2];
    const void* wk  = d_in[3];
    const void* bk  = d_in[4];
    const void* wv  = d_in[5];
    const void* bv  = d_in[6];
    const void* wo  = d_in[7];
    const void* bo  = d_in[8];
    const void* pos = d_in[9];

    int*   flag  = (int*)d_ws;
    float* slab0 = (float*)((char*)d_ws + 256);

    // Chunk the 32 (b,t) slices to what the workspace holds.
    // Full batch needs 256 B + 3*32*1.18 MB = ~113 MB.
    const size_t per_bt = (size_t)3 * SLABF * sizeof(float);
    int chunk = 1;
    if (ws_size > 256 + per_bt) {
        size_t c = (ws_size - 256) / per_bt;
        chunk = (c > 32) ? 32 : (int)c;
    }

    detect_dtype<<<1, 256, 0, stream>>>((const ushort_t*)wq, flag);

    for (int bt0 = 0; bt0 < 32; bt0 += chunk) {
        const int nbt = (32 - bt0 < chunk) ? (32 - bt0) : chunk;
        float* qslab = slab0;
        float* kslab = qslab + (size_t)nbt * SLABF;
        float* vslab = kslab + (size_t)nbt * SLABF;

        proj_qkv_gemm<<<dim3(9, 8, nbt * 3), 256, 0, stream>>>(
            x, pos, wq, bq, wk, bk, wv, bv, qslab, kslab, vslab, flag, bt0);
        attn_batched<<<dim3(3, 8, nbt), 192, 0, stream>>>(qslab, kslab, vslab);
        proj_out_gemm<<<dim3(9, 8, nbt), 256, 0, stream>>>(
            qslab, wo, bo, d_out, flag, bt0);
    }
}

// Round 2
// 3749.822 us; speedup vs baseline: 17.4831x; 3.1221x over previous
//
#include <hip/hip_runtime.h>
#include <math.h>

typedef unsigned short ushort_t;

#define SLABF (512 * 576)   /* floats per (b,t) scratch slab */

__device__ __forceinline__ float bf2f(ushort_t u) {
    union { unsigned int i; float f; } v;
    v.i = ((unsigned int)u) << 16;
    return v.f;
}
__device__ __forceinline__ ushort_t f2bf(float f) {
    union { float f; unsigned int i; } v;
    v.f = f;
    unsigned int r = v.i + 0x7FFFu + ((v.i >> 16) & 1u);
    return (ushort_t)(r >> 16);
}

// Read input element i from a buffer whose true dtype is selected by flag.
__device__ __forceinline__ float in_read(const void* p, size_t i, int is_f32) {
    if (is_f32) return ((const float*)p)[i];
    return bf2f(((const ushort_t*)p)[i]);
}

// ---------------------------------------------------------------------------
// Dtype probe (unchanged).
// ---------------------------------------------------------------------------
__global__ void detect_dtype(const ushort_t* wq_h, int* flag) {
    __shared__ int cnt;
    if (threadIdx.x == 0) cnt = 0;
    __syncthreads();
    int local = 0;
    for (int i = threadIdx.x; i < 4096; i += 256) {
        float v = bf2f(wq_h[i]);
        if (!(fabsf(v) < 1e6f)) local++;
    }
    atomicAdd(&cnt, local);
    __syncthreads();
    if (threadIdx.x == 0) flag[0] = (cnt > 10) ? 1 : 0;
}

// ---------------------------------------------------------------------------
// Fused QKV projection, tiled GEMM, batched over (b,t) chunk.
// Q slab layout: [h][d][p]   (o-major, as before -> feeds proj_out unchanged)
// K/V slab layout: [h][kv][d] (TRANSPOSED -> attention reads contiguous rows)
// Tile: 64 o x 64 p, BK=16. 256 threads, 4x4 microtile each.
// grid: (9 p-tiles, 8 o-tiles, nbt*3) with z = btl*3 + mode.
// NOTE: o-tile (64) == head size, so blockIdx.y is exactly the head index.
// ---------------------------------------------------------------------------
__global__ __launch_bounds__(256)
void proj_qkv_gemm(const void* __restrict__ x, const void* __restrict__ pos,
                   const void* __restrict__ w0, const void* __restrict__ b0,
                   const void* __restrict__ w1, const void* __restrict__ b1,
                   const void* __restrict__ w2, const void* __restrict__ b2,
                   float* __restrict__ qs, float* __restrict__ ks, float* __restrict__ vs,
                   const int* __restrict__ flag, int bt_base)
{
    const int is_f32 = flag[0];
    const int z = blockIdx.z;
    const int btl = z / 3;
    const int mode = z - btl * 3;
    const int bt = bt_base + btl;
    const int b = bt >> 4, t = bt & 15;

    const void* W; const void* bias; float* out;
    if (mode == 0)      { W = w0; bias = b0; out = qs; }
    else if (mode == 1) { W = w1; bias = b1; out = ks; }
    else                { W = w2; bias = b2; out = vs; }
    out += (size_t)btl * SLABF;

    const int o0 = blockIdx.y * 64;
    const int p0 = blockIdx.x * 64;
    const int tid = threadIdx.x;
    const int tx = tid & 15;   // p microtile index
    const int ty = tid >> 4;   // o microtile index

    __shared__ float  As[16][68];   // [c][o], padded
    __shared__ float4 Bs[16][17];   // [c][p/4], padded

    float acc[4][4];
    #pragma unroll
    for (int r = 0; r < 4; ++r) {
        float bb = in_read(bias, (size_t)(o0 + ty * 4 + r), is_f32);
        #pragma unroll
        for (int j = 0; j < 4; ++j) acc[r][j] = bb;
    }

    const int wo_l = tid >> 2;
    const int wc_l = (tid & 3) * 4;
    const int xc_l = ty;
    const int xp_l = tx * 4;

    for (int c0 = 0; c0 < 512; c0 += 16) {
        {
            size_t wbase = (size_t)(o0 + wo_l) * 512 + (size_t)(c0 + wc_l);
            #pragma unroll
            for (int i = 0; i < 4; ++i)
                As[wc_l + i][wo_l] = in_read(W, wbase + i, is_f32);
        }
        {
            float pv = in_read(pos, (size_t)(c0 + xc_l) * 16 + t, is_f32);
            size_t xbase = ((size_t)(b * 512 + c0 + xc_l) * 16 + t) * 576 + p0 + xp_l;
            float4 xv;
            xv.x = in_read(x, xbase + 0, is_f32) + pv;
            xv.y = in_read(x, xbase + 1, is_f32) + pv;
            xv.z = in_read(x, xbase + 2, is_f32) + pv;
            xv.w = in_read(x, xbase + 3, is_f32) + pv;
            Bs[xc_l][tx] = xv;
        }
        __syncthreads();
        #pragma unroll
        for (int kk = 0; kk < 16; ++kk) {
            float4 bv = Bs[kk][tx];
            #pragma unroll
            for (int r = 0; r < 4; ++r) {
                float a = As[kk][ty * 4 + r];
                acc[r][0] += a * bv.x;
                acc[r][1] += a * bv.y;
                acc[r][2] += a * bv.z;
                acc[r][3] += a * bv.w;
            }
        }
        __syncthreads();
    }

    if (mode == 0) {
        // Q: [h][d][p] == [o][p]
        #pragma unroll
        for (int r = 0; r < 4; ++r) {
            float4 st;
            st.x = acc[r][0]; st.y = acc[r][1]; st.z = acc[r][2]; st.w = acc[r][3];
            *(float4*)&out[(size_t)(o0 + ty * 4 + r) * 576 + p0 + tx * 4] = st;
        }
    } else {
        // K/V: [h][p][d]; addr = o0*576 + p*64 + d', d' = ty*4 + r (contiguous)
        #pragma unroll
        for (int j = 0; j < 4; ++j) {
            float4 st;
            st.x = acc[0][j]; st.y = acc[1][j]; st.z = acc[2][j]; st.w = acc[3][j];
            *(float4*)&out[(size_t)o0 * 576 +
                           (size_t)(p0 + tx * 4 + j) * 64 + ty * 4] = st;
        }
    }
}

// ---------------------------------------------------------------------------
// Attention, lane-pair split over head_dim, batched over (b,t) chunk.
// grid (6, 8, nbt), block 192. Thread (q, half): half = tid&1 owns d-range
// [half*32, half*32+32). K/V read from transposed [h][kv][64] slabs as
// contiguous float4 rows; score halves combined with one __shfl_xor.
// AO overwrites Q in place: each thread reads/writes only its own
// (q, d-half) cells, so no cross-thread hazard.
// ---------------------------------------------------------------------------
__global__ __launch_bounds__(192)
void attn_split(float* __restrict__ qs, const float* __restrict__ ks,
                const float* __restrict__ vs)
{
    const size_t slab = (size_t)blockIdx.z * SLABF;
    const int h = blockIdx.y;
    const int tid = threadIdx.x;
    const int q = blockIdx.x * 96 + (tid >> 1);   // 0..575
    const int d0 = (tid & 1) * 32;

    float* __restrict__ Q = qs + slab + (size_t)(h * 64) * 576;     // [d][576]
    const float* __restrict__ Kt = ks + slab + (size_t)h * (576 * 64); // [kv][64]
    const float* __restrict__ Vt = vs + slab + (size_t)h * (576 * 64);

    float4 Q4[8];
    #pragma unroll
    for (int j = 0; j < 8; ++j) {
        const int d = d0 + j * 4;
        float4 v;
        v.x = Q[(size_t)(d + 0) * 576 + q] * 0.125f;
        v.y = Q[(size_t)(d + 1) * 576 + q] * 0.125f;
        v.z = Q[(size_t)(d + 2) * 576 + q] * 0.125f;
        v.w = Q[(size_t)(d + 3) * 576 + q] * 0.125f;
        Q4[j] = v;
    }

    float4 O4[8];
    #pragma unroll
    for (int j = 0; j < 8; ++j) { O4[j].x = 0.f; O4[j].y = 0.f; O4[j].z = 0.f; O4[j].w = 0.f; }
    float l = 0.f;

    #pragma unroll 2
    for (int kv = 0; kv < 576; ++kv) {
        const float4* __restrict__ Krow = (const float4*)(Kt + (size_t)kv * 64 + d0);
        float s0 = 0.f, s1 = 0.f, s2 = 0.f, s3 = 0.f;
        #pragma unroll
        for (int j = 0; j < 8; ++j) {
            float4 kj = Krow[j];
            s0 += Q4[j].x * kj.x;
            s1 += Q4[j].y * kj.y;
            s2 += Q4[j].z * kj.z;
            s3 += Q4[j].w * kj.w;
        }
        float sp = (s0 + s1) + (s2 + s3);
        float s = sp + __shfl_xor(sp, 1);
        float e = __expf(s);
        l += e;

        const float4* __restrict__ Vrow = (const float4*)(Vt + (size_t)kv * 64 + d0);
        #pragma unroll
        for (int j = 0; j < 8; ++j) {
            float4 vj = Vrow[j];
            O4[j].x += e * vj.x;
            O4[j].y += e * vj.y;
            O4[j].z += e * vj.z;
            O4[j].w += e * vj.w;
        }
    }

    const float inv = 1.f / l;
    #pragma unroll
    for (int j = 0; j < 8; ++j) {
        const int d = d0 + j * 4;
        Q[(size_t)(d + 0) * 576 + q] = O4[j].x * inv;
        Q[(size_t)(d + 1) * 576 + q] = O4[j].y * inv;
        Q[(size_t)(d + 2) * 576 + q] = O4[j].z * inv;
        Q[(size_t)(d + 3) * 576 + q] = O4[j].w * inv;
    }
}

// ---------------------------------------------------------------------------
// Output projection, tiled GEMM, batched over (b,t) chunk (unchanged; AO is
// still [c][p] because attention writes O back into the Q slab's layout).
// ---------------------------------------------------------------------------
__global__ __launch_bounds__(256)
void proj_out_gemm(const float* __restrict__ ao,
                   const void* __restrict__ wo, const void* __restrict__ bo,
                   void* __restrict__ out, const int* __restrict__ flag, int bt_base)
{
    const int is_f32 = flag[0];
    const int btl = blockIdx.z;
    const int bt = bt_base + btl;
    const int b = bt >> 4, t = bt & 15;
    const float* A = ao + (size_t)btl * SLABF;

    const int o0 = blockIdx.y * 64;
    const int p0 = blockIdx.x * 64;
    const int tid = threadIdx.x;
    const int tx = tid & 15;
    const int ty = tid >> 4;

    __shared__ float  As[16][68];
    __shared__ float4 Bs[16][17];

    float acc[4][4];
    #pragma unroll
    for (int r = 0; r < 4; ++r) {
        float bb = in_read(bo, (size_t)(o0 + ty * 4 + r), is_f32);
        #pragma unroll
        for (int j = 0; j < 4; ++j) acc[r][j] = bb;
    }

    const int wo_l = tid >> 2;
    const int wc_l = (tid & 3) * 4;
    const int xc_l = ty;
    const int xp_l = tx * 4;

    for (int c0 = 0; c0 < 512; c0 += 16) {
        {
            size_t wbase = (size_t)(o0 + wo_l) * 512 + (size_t)(c0 + wc_l);
            #pragma unroll
            for (int i = 0; i < 4; ++i)
                As[wc_l + i][wo_l] = in_read(wo, wbase + i, is_f32);
        }
        Bs[xc_l][tx] = *(const float4*)&A[(size_t)(c0 + xc_l) * 576 + p0 + xp_l];
        __syncthreads();
        #pragma unroll
        for (int kk = 0; kk < 16; ++kk) {
            float4 bv = Bs[kk][tx];
            #pragma unroll
            for (int r = 0; r < 4; ++r) {
                float a = As[kk][ty * 4 + r];
                acc[r][0] += a * bv.x;
                acc[r][1] += a * bv.y;
                acc[r][2] += a * bv.z;
                acc[r][3] += a * bv.w;
            }
        }
        __syncthreads();
    }

    #pragma unroll
    for (int r = 0; r < 4; ++r) {
        const int o = o0 + ty * 4 + r;
        const size_t addr = ((size_t)(b * 512 + o) * 16 + t) * 576 + p0 + tx * 4;
        if (is_f32) {
            float4 st;
            st.x = acc[r][0]; st.y = acc[r][1]; st.z = acc[r][2]; st.w = acc[r][3];
            *(float4*)((float*)out + addr) = st;
        } else {
            unsigned int lo = (unsigned int)f2bf(acc[r][0]) |
                              ((unsigned int)f2bf(acc[r][1]) << 16);
            unsigned int hi = (unsigned int)f2bf(acc[r][2]) |
                              ((unsigned int)f2bf(acc[r][3]) << 16);
            uint2 st; st.x = lo; st.y = hi;
            *(uint2*)((ushort_t*)out + addr) = st;
        }
    }
}

extern "C" void kernel_launch(void* const* d_in, const int* in_sizes, int n_in,
                              void* d_out, int out_size, void* d_ws, size_t ws_size,
                              hipStream_t stream)
{
    (void)in_sizes; (void)n_in; (void)out_size;
    const void* x   = d_in[0];
    const void* wq  = d_in[1];
    const void* bq  = d_in[2];
    const void* wk  = d_in[3];
    const void* bk  = d_in[4];
    const void* wv  = d_in[5];
    const void* bv  = d_in[6];
    const void* wo  = d_in[7];
    const void* bo  = d_in[8];
    const void* pos = d_in[9];

    int*   flag  = (int*)d_ws;
    float* slab0 = (float*)((char*)d_ws + 256);

    const size_t per_bt = (size_t)3 * SLABF * sizeof(float);
    int chunk = 1;
    if (ws_size > 256 + per_bt) {
        size_t c = (ws_size - 256) / per_bt;
        chunk = (c > 32) ? 32 : (int)c;
    }

    detect_dtype<<<1, 256, 0, stream>>>((const ushort_t*)wq, flag);

    for (int bt0 = 0; bt0 < 32; bt0 += chunk) {
        const int nbt = (32 - bt0 < chunk) ? (32 - bt0) : chunk;
        float* qslab = slab0;
        float* kslab = qslab + (size_t)nbt * SLABF;
        float* vslab = kslab + (size_t)nbt * SLABF;

        proj_qkv_gemm<<<dim3(9, 8, nbt * 3), 256, 0, stream>>>(
            x, pos, wq, bq, wk, bk, wv, bv, qslab, kslab, vslab, flag, bt0);
        attn_split<<<dim3(6, 8, nbt), 192, 0, stream>>>(qslab, kslab, vslab);
        proj_out_gemm<<<dim3(9, 8, nbt), 256, 0, stream>>>(
            qslab, wo, bo, d_out, flag, bt0);
    }
}

// Round 4
// 3310.565 us; speedup vs baseline: 19.8028x; 1.1327x over previous
//
#include <hip/hip_runtime.h>
#include <math.h>

typedef unsigned short ushort_t;

#define SLABF (512 * 576)   /* floats per (b,t) scratch slab */

__device__ __forceinline__ float bf2f(ushort_t u) {
    union { unsigned int i; float f; } v;
    v.i = ((unsigned int)u) << 16;
    return v.f;
}
__device__ __forceinline__ ushort_t f2bf(float f) {
    union { float f; unsigned int i; } v;
    v.f = f;
    unsigned int r = v.i + 0x7FFFu + ((v.i >> 16) & 1u);
    return (ushort_t)(r >> 16);
}

// Read input element i from a buffer whose true dtype is selected by flag.
__device__ __forceinline__ float in_read(const void* p, size_t i, int is_f32) {
    if (is_f32) return ((const float*)p)[i];
    return bf2f(((const ushort_t*)p)[i]);
}

// ---------------------------------------------------------------------------
// Dtype probe (unchanged).
// ---------------------------------------------------------------------------
__global__ void detect_dtype(const ushort_t* wq_h, int* flag) {
    __shared__ int cnt;
    if (threadIdx.x == 0) cnt = 0;
    __syncthreads();
    int local = 0;
    for (int i = threadIdx.x; i < 4096; i += 256) {
        float v = bf2f(wq_h[i]);
        if (!(fabsf(v) < 1e6f)) local++;
    }
    atomicAdd(&cnt, local);
    __syncthreads();
    if (threadIdx.x == 0) flag[0] = (cnt > 10) ? 1 : 0;
}

// ---------------------------------------------------------------------------
// Fused QKV projection, tiled GEMM, batched over (b,t) chunk.
// Q slab layout: [h][d][p]   (o-major -> feeds proj_out unchanged)
// K/V slab layout: [h][kv][d] (transposed -> attention reads contiguous rows)
// Tile: 64 o x 64 p, BK=16. 256 threads, 4x4 microtile each.
// grid: (9 p-tiles, 8 o-tiles, nbt*3) with z = btl*3 + mode.
// ---------------------------------------------------------------------------
__global__ __launch_bounds__(256)
void proj_qkv_gemm(const void* __restrict__ x, const void* __restrict__ pos,
                   const void* __restrict__ w0, const void* __restrict__ b0,
                   const void* __restrict__ w1, const void* __restrict__ b1,
                   const void* __restrict__ w2, const void* __restrict__ b2,
                   float* __restrict__ qs, float* __restrict__ ks, float* __restrict__ vs,
                   const int* __restrict__ flag, int bt_base)
{
    const int is_f32 = flag[0];
    const int z = blockIdx.z;
    const int btl = z / 3;
    const int mode = z - btl * 3;
    const int bt = bt_base + btl;
    const int b = bt >> 4, t = bt & 15;

    const void* W; const void* bias; float* out;
    if (mode == 0)      { W = w0; bias = b0; out = qs; }
    else if (mode == 1) { W = w1; bias = b1; out = ks; }
    else                { W = w2; bias = b2; out = vs; }
    out += (size_t)btl * SLABF;

    const int o0 = blockIdx.y * 64;
    const int p0 = blockIdx.x * 64;
    const int tid = threadIdx.x;
    const int tx = tid & 15;   // p microtile index
    const int ty = tid >> 4;   // o microtile index

    __shared__ float  As[16][68];   // [c][o], padded
    __shared__ float4 Bs[16][17];   // [c][p/4], padded

    float acc[4][4];
    #pragma unroll
    for (int r = 0; r < 4; ++r) {
        float bb = in_read(bias, (size_t)(o0 + ty * 4 + r), is_f32);
        #pragma unroll
        for (int j = 0; j < 4; ++j) acc[r][j] = bb;
    }

    const int wo_l = tid >> 2;
    const int wc_l = (tid & 3) * 4;
    const int xc_l = ty;
    const int xp_l = tx * 4;

    for (int c0 = 0; c0 < 512; c0 += 16) {
        {
            size_t wbase = (size_t)(o0 + wo_l) * 512 + (size_t)(c0 + wc_l);
            #pragma unroll
            for (int i = 0; i < 4; ++i)
                As[wc_l + i][wo_l] = in_read(W, wbase + i, is_f32);
        }
        {
            float pv = in_read(pos, (size_t)(c0 + xc_l) * 16 + t, is_f32);
            size_t xbase = ((size_t)(b * 512 + c0 + xc_l) * 16 + t) * 576 + p0 + xp_l;
            float4 xv;
            xv.x = in_read(x, xbase + 0, is_f32) + pv;
            xv.y = in_read(x, xbase + 1, is_f32) + pv;
            xv.z = in_read(x, xbase + 2, is_f32) + pv;
            xv.w = in_read(x, xbase + 3, is_f32) + pv;
            Bs[xc_l][tx] = xv;
        }
        __syncthreads();
        #pragma unroll
        for (int kk = 0; kk < 16; ++kk) {
            float4 bv = Bs[kk][tx];
            #pragma unroll
            for (int r = 0; r < 4; ++r) {
                float a = As[kk][ty * 4 + r];
                acc[r][0] += a * bv.x;
                acc[r][1] += a * bv.y;
                acc[r][2] += a * bv.z;
                acc[r][3] += a * bv.w;
            }
        }
        __syncthreads();
    }

    if (mode == 0) {
        // Q: [h][d][p] == [o][p]
        #pragma unroll
        for (int r = 0; r < 4; ++r) {
            float4 st;
            st.x = acc[r][0]; st.y = acc[r][1]; st.z = acc[r][2]; st.w = acc[r][3];
            *(float4*)&out[(size_t)(o0 + ty * 4 + r) * 576 + p0 + tx * 4] = st;
        }
    } else {
        // K/V: [h][p][d]; addr = o0*576 + p*64 + d', d' = ty*4 (contiguous 4)
        #pragma unroll
        for (int j = 0; j < 4; ++j) {
            float4 st;
            st.x = acc[0][j]; st.y = acc[1][j]; st.z = acc[2][j]; st.w = acc[3][j];
            *(float4*)&out[(size_t)o0 * 576 +
                           (size_t)(p0 + tx * 4 + j) * 64 + ty * 4] = st;
        }
    }
}

// ---------------------------------------------------------------------------
// Attention, 4-lane d-split per query, XCD-chunked 1-D grid.
// Block = 256 threads: 64 queries x 4 d-groups (16 d each).
// Work unit = (pair = btl*8+h, q-tile of 64); 9 q-tiles per pair.
// XCD mapping: assuming hw round-robins consecutive blocks over 8 XCDs,
// L -> w = (L&7)*(nbt*9) + (L>>3) gives each XCD nbt whole pairs, so one
// pair's K/V (294 KB) streams through a single XCD L2. Perf-only heuristic.
// Score reduce: 2x __shfl_xor across the 4-lane group; exp redundant x4.
// AO overwrites Q in place: each thread touches only its own (q, d-range).
// ---------------------------------------------------------------------------
__global__ __launch_bounds__(256)
void attn_d4(float* __restrict__ qs, const float* __restrict__ ks,
             const float* __restrict__ vs, int nbt)
{
    const int L = blockIdx.x;
    const int w = (L & 7) * (nbt * 9) + (L >> 3);
    const int pair = w / 9;
    const int qt = w - pair * 9;
    const int btl = pair >> 3;
    const int h = pair & 7;

    const int tid = threadIdx.x;
    const int ql = tid >> 2;          // query within tile: 0..63
    const int dg = tid & 3;           // d-group: 0..3
    const int d0 = dg * 16;
    const int q = qt * 64 + ql;

    const size_t slab = (size_t)btl * SLABF;
    float* __restrict__ Q = qs + slab + (size_t)(h * 64) * 576;        // [d][576]
    const float* __restrict__ Kt = ks + slab + (size_t)h * (576 * 64); // [kv][64]
    const float* __restrict__ Vt = vs + slab + (size_t)h * (576 * 64);

    float4 Q4[4];
    #pragma unroll
    for (int j = 0; j < 4; ++j) {
        const int d = d0 + j * 4;
        float4 v;
        v.x = Q[(size_t)(d + 0) * 576 + q] * 0.125f;
        v.y = Q[(size_t)(d + 1) * 576 + q] * 0.125f;
        v.z = Q[(size_t)(d + 2) * 576 + q] * 0.125f;
        v.w = Q[(size_t)(d + 3) * 576 + q] * 0.125f;
        Q4[j] = v;
    }

    float4 O4[4];
    #pragma unroll
    for (int j = 0; j < 4; ++j) { O4[j].x = 0.f; O4[j].y = 0.f; O4[j].z = 0.f; O4[j].w = 0.f; }
    float l = 0.f;

    const float4* __restrict__ Kp = (const float4*)(Kt + d0);
    const float4* __restrict__ Vp = (const float4*)(Vt + d0);

    for (int kv = 0; kv < 576; ++kv) {
        float s0 = 0.f, s1 = 0.f, s2 = 0.f, s3 = 0.f;
        #pragma unroll
        for (int j = 0; j < 4; ++j) {
            float4 kj = Kp[(size_t)kv * 16 + j];
            s0 += Q4[j].x * kj.x;
            s1 += Q4[j].y * kj.y;
            s2 += Q4[j].z * kj.z;
            s3 += Q4[j].w * kj.w;
        }
        float sp = (s0 + s1) + (s2 + s3);
        sp += __shfl_xor(sp, 1);
        sp += __shfl_xor(sp, 2);
        float e = __expf(sp);
        l += e;

        #pragma unroll
        for (int j = 0; j < 4; ++j) {
            float4 vj = Vp[(size_t)kv * 16 + j];
            O4[j].x += e * vj.x;
            O4[j].y += e * vj.y;
            O4[j].z += e * vj.z;
            O4[j].w += e * vj.w;
        }
    }

    const float inv = 1.f / l;
    #pragma unroll
    for (int j = 0; j < 4; ++j) {
        const int d = d0 + j * 4;
        Q[(size_t)(d + 0) * 576 + q] = O4[j].x * inv;
        Q[(size_t)(d + 1) * 576 + q] = O4[j].y * inv;
        Q[(size_t)(d + 2) * 576 + q] = O4[j].z * inv;
        Q[(size_t)(d + 3) * 576 + q] = O4[j].w * inv;
    }
}

// ---------------------------------------------------------------------------
// Output projection, tiled GEMM, batched over (b,t) chunk (unchanged).
// ---------------------------------------------------------------------------
__global__ __launch_bounds__(256)
void proj_out_gemm(const float* __restrict__ ao,
                   const void* __restrict__ wo, const void* __restrict__ bo,
                   void* __restrict__ out, const int* __restrict__ flag, int bt_base)
{
    const int is_f32 = flag[0];
    const int btl = blockIdx.z;
    const int bt = bt_base + btl;
    const int b = bt >> 4, t = bt & 15;
    const float* A = ao + (size_t)btl * SLABF;

    const int o0 = blockIdx.y * 64;
    const int p0 = blockIdx.x * 64;
    const int tid = threadIdx.x;
    const int tx = tid & 15;
    const int ty = tid >> 4;

    __shared__ float  As[16][68];
    __shared__ float4 Bs[16][17];

    float acc[4][4];
    #pragma unroll
    for (int r = 0; r < 4; ++r) {
        float bb = in_read(bo, (size_t)(o0 + ty * 4 + r), is_f32);
        #pragma unroll
        for (int j = 0; j < 4; ++j) acc[r][j] = bb;
    }

    const int wo_l = tid >> 2;
    const int wc_l = (tid & 3) * 4;
    const int xc_l = ty;
    const int xp_l = tx * 4;

    for (int c0 = 0; c0 < 512; c0 += 16) {
        {
            size_t wbase = (size_t)(o0 + wo_l) * 512 + (size_t)(c0 + wc_l);
            #pragma unroll
            for (int i = 0; i < 4; ++i)
                As[wc_l + i][wo_l] = in_read(wo, wbase + i, is_f32);
        }
        Bs[xc_l][tx] = *(const float4*)&A[(size_t)(c0 + xc_l) * 576 + p0 + xp_l];
        __syncthreads();
        #pragma unroll
        for (int kk = 0; kk < 16; ++kk) {
            float4 bv = Bs[kk][tx];
            #pragma unroll
            for (int r = 0; r < 4; ++r) {
                float a = As[kk][ty * 4 + r];
                acc[r][0] += a * bv.x;
                acc[r][1] += a * bv.y;
                acc[r][2] += a * bv.z;
                acc[r][3] += a * bv.w;
            }
        }
        __syncthreads();
    }

    #pragma unroll
    for (int r = 0; r < 4; ++r) {
        const int o = o0 + ty * 4 + r;
        const size_t addr = ((size_t)(b * 512 + o) * 16 + t) * 576 + p0 + tx * 4;
        if (is_f32) {
            float4 st;
            st.x = acc[r][0]; st.y = acc[r][1]; st.z = acc[r][2]; st.w = acc[r][3];
            *(float4*)((float*)out + addr) = st;
        } else {
            unsigned int lo = (unsigned int)f2bf(acc[r][0]) |
                              ((unsigned int)f2bf(acc[r][1]) << 16);
            unsigned int hi = (unsigned int)f2bf(acc[r][2]) |
                              ((unsigned int)f2bf(acc[r][3]) << 16);
            uint2 st; st.x = lo; st.y = hi;
            *(uint2*)((ushort_t*)out + addr) = st;
        }
    }
}

extern "C" void kernel_launch(void* const* d_in, const int* in_sizes, int n_in,
                              void* d_out, int out_size, void* d_ws, size_t ws_size,
                              hipStream_t stream)
{
    (void)in_sizes; (void)n_in; (void)out_size;
    const void* x   = d_in[0];
    const void* wq  = d_in[1];
    const void* bq  = d_in[2];
    const void* wk  = d_in[3];
    const void* bk  = d_in[4];
    const void* wv  = d_in[5];
    const void* bv  = d_in[6];
    const void* wo  = d_in[7];
    const void* bo  = d_in[8];
    const void* pos = d_in[9];

    int*   flag  = (int*)d_ws;
    float* slab0 = (float*)((char*)d_ws + 256);

    const size_t per_bt = (size_t)3 * SLABF * sizeof(float);
    int chunk = 1;
    if (ws_size > 256 + per_bt) {
        size_t c = (ws_size - 256) / per_bt;
        chunk = (c > 32) ? 32 : (int)c;
    }
    if (chunk < 1) chunk = 1;

    detect_dtype<<<1, 256, 0, stream>>>((const ushort_t*)wq, flag);

    for (int bt0 = 0; bt0 < 32; bt0 += chunk) {
        const int nbt = (32 - bt0 < chunk) ? (32 - bt0) : chunk;
        float* qslab = slab0;
        float* kslab = qslab + (size_t)nbt * SLABF;
        float* vslab = kslab + (size_t)nbt * SLABF;

        proj_qkv_gemm<<<dim3(9, 8, nbt * 3), 256, 0, stream>>>(
            x, pos, wq, bq, wk, bk, wv, bv, qslab, kslab, vslab, flag, bt0);
        attn_d4<<<dim3(nbt * 72), 256, 0, stream>>>(qslab, kslab, vslab, nbt);
        proj_out_gemm<<<dim3(9, 8, nbt), 256, 0, stream>>>(
            qslab, wo, bo, d_out, flag, bt0);
    }
}

// Round 5
// 1611.406 us; speedup vs baseline: 40.6840x; 2.0545x over previous
//
#include <hip/hip_runtime.h>
#include <math.h>

typedef unsigned short ushort_t;

#define SLABF (512 * 576)   /* floats per (b,t) scratch slab */
#define KVT   32            /* kv tile rows staged in LDS */
#define LDP   68            /* padded LDS row length (floats): 64+4 */

__device__ __forceinline__ float bf2f(ushort_t u) {
    union { unsigned int i; float f; } v;
    v.i = ((unsigned int)u) << 16;
    return v.f;
}
__device__ __forceinline__ ushort_t f2bf(float f) {
    union { float f; unsigned int i; } v;
    v.f = f;
    unsigned int r = v.i + 0x7FFFu + ((v.i >> 16) & 1u);
    return (ushort_t)(r >> 16);
}

// Read input element i from a buffer whose true dtype is selected by flag.
__device__ __forceinline__ float in_read(const void* p, size_t i, int is_f32) {
    if (is_f32) return ((const float*)p)[i];
    return bf2f(((const ushort_t*)p)[i]);
}

// ---------------------------------------------------------------------------
// Dtype probe (unchanged).
// ---------------------------------------------------------------------------
__global__ void detect_dtype(const ushort_t* wq_h, int* flag) {
    __shared__ int cnt;
    if (threadIdx.x == 0) cnt = 0;
    __syncthreads();
    int local = 0;
    for (int i = threadIdx.x; i < 4096; i += 256) {
        float v = bf2f(wq_h[i]);
        if (!(fabsf(v) < 1e6f)) local++;
    }
    atomicAdd(&cnt, local);
    __syncthreads();
    if (threadIdx.x == 0) flag[0] = (cnt > 10) ? 1 : 0;
}

// ---------------------------------------------------------------------------
// Fused QKV projection, tiled GEMM, batched over (b,t) chunk (unchanged).
// Q slab layout: [h][d][p]; K/V slab layout: [h][kv][d] (transposed).
// ---------------------------------------------------------------------------
__global__ __launch_bounds__(256)
void proj_qkv_gemm(const void* __restrict__ x, const void* __restrict__ pos,
                   const void* __restrict__ w0, const void* __restrict__ b0,
                   const void* __restrict__ w1, const void* __restrict__ b1,
                   const void* __restrict__ w2, const void* __restrict__ b2,
                   float* __restrict__ qs, float* __restrict__ ks, float* __restrict__ vs,
                   const int* __restrict__ flag, int bt_base)
{
    const int is_f32 = flag[0];
    const int z = blockIdx.z;
    const int btl = z / 3;
    const int mode = z - btl * 3;
    const int bt = bt_base + btl;
    const int b = bt >> 4, t = bt & 15;

    const void* W; const void* bias; float* out;
    if (mode == 0)      { W = w0; bias = b0; out = qs; }
    else if (mode == 1) { W = w1; bias = b1; out = ks; }
    else                { W = w2; bias = b2; out = vs; }
    out += (size_t)btl * SLABF;

    const int o0 = blockIdx.y * 64;
    const int p0 = blockIdx.x * 64;
    const int tid = threadIdx.x;
    const int tx = tid & 15;   // p microtile index
    const int ty = tid >> 4;   // o microtile index

    __shared__ float  As[16][68];   // [c][o], padded
    __shared__ float4 Bs[16][17];   // [c][p/4], padded

    float acc[4][4];
    #pragma unroll
    for (int r = 0; r < 4; ++r) {
        float bb = in_read(bias, (size_t)(o0 + ty * 4 + r), is_f32);
        #pragma unroll
        for (int j = 0; j < 4; ++j) acc[r][j] = bb;
    }

    const int wo_l = tid >> 2;
    const int wc_l = (tid & 3) * 4;
    const int xc_l = ty;
    const int xp_l = tx * 4;

    for (int c0 = 0; c0 < 512; c0 += 16) {
        {
            size_t wbase = (size_t)(o0 + wo_l) * 512 + (size_t)(c0 + wc_l);
            #pragma unroll
            for (int i = 0; i < 4; ++i)
                As[wc_l + i][wo_l] = in_read(W, wbase + i, is_f32);
        }
        {
            float pv = in_read(pos, (size_t)(c0 + xc_l) * 16 + t, is_f32);
            size_t xbase = ((size_t)(b * 512 + c0 + xc_l) * 16 + t) * 576 + p0 + xp_l;
            float4 xv;
            xv.x = in_read(x, xbase + 0, is_f32) + pv;
            xv.y = in_read(x, xbase + 1, is_f32) + pv;
            xv.z = in_read(x, xbase + 2, is_f32) + pv;
            xv.w = in_read(x, xbase + 3, is_f32) + pv;
            Bs[xc_l][tx] = xv;
        }
        __syncthreads();
        #pragma unroll
        for (int kk = 0; kk < 16; ++kk) {
            float4 bv = Bs[kk][tx];
            #pragma unroll
            for (int r = 0; r < 4; ++r) {
                float a = As[kk][ty * 4 + r];
                acc[r][0] += a * bv.x;
                acc[r][1] += a * bv.y;
                acc[r][2] += a * bv.z;
                acc[r][3] += a * bv.w;
            }
        }
        __syncthreads();
    }

    if (mode == 0) {
        #pragma unroll
        for (int r = 0; r < 4; ++r) {
            float4 st;
            st.x = acc[r][0]; st.y = acc[r][1]; st.z = acc[r][2]; st.w = acc[r][3];
            *(float4*)&out[(size_t)(o0 + ty * 4 + r) * 576 + p0 + tx * 4] = st;
        }
    } else {
        #pragma unroll
        for (int j = 0; j < 4; ++j) {
            float4 st;
            st.x = acc[0][j]; st.y = acc[1][j]; st.z = acc[2][j]; st.w = acc[3][j];
            *(float4*)&out[(size_t)o0 * 576 +
                           (size_t)(p0 + tx * 4 + j) * 64 + ty * 4] = st;
        }
    }
}

// ---------------------------------------------------------------------------
// Attention, 4-lane d-split per query, LDS-staged double-buffered K/V tiles.
// Block = 256 threads: 64 queries x 4 d-groups (16 d each); 9 q-tiles/pair.
// XCD-chunked 1-D grid as before.
// Staging (T14 split): issue 4 global float4 loads for tile t+1 BEFORE the
// compute of tile t; ds_write them AFTER the barrier. Global latency hides
// under ~32 kv steps of LDS compute. LDS rows padded to 68 floats so stage
// writes and fragment reads are <=2-way bank aliases (free).
// AO overwrites Q in place (thread-private columns).
// ---------------------------------------------------------------------------
__global__ __launch_bounds__(256)
void attn_lds(float* __restrict__ qs, const float* __restrict__ ks,
              const float* __restrict__ vs, int nbt)
{
    const int L = blockIdx.x;
    const int w = (L & 7) * (nbt * 9) + (L >> 3);
    const int pair = w / 9;
    const int qt = w - pair * 9;
    const int btl = pair >> 3;
    const int h = pair & 7;

    const int tid = threadIdx.x;
    const int ql = tid >> 2;          // query within tile: 0..63
    const int dg = tid & 3;           // d-group: 0..3
    const int d0 = dg * 16;
    const int q = qt * 64 + ql;

    const size_t slab = (size_t)btl * SLABF;
    float* __restrict__ Q = qs + slab + (size_t)(h * 64) * 576;        // [d][576]
    const float* __restrict__ Kt = ks + slab + (size_t)h * (576 * 64); // [kv][64]
    const float* __restrict__ Vt = vs + slab + (size_t)h * (576 * 64);

    __shared__ float Ks_[2][KVT][LDP];
    __shared__ float Vs_[2][KVT][LDP];

    // stage mapping: thread loads K row lr cols [lc, lc+8) and same for V
    const int lr = tid >> 3;          // 0..31
    const int lc = (tid & 7) * 8;     // 0..56

    float4 Q4[4];
    #pragma unroll
    for (int j = 0; j < 4; ++j) {
        const int d = d0 + j * 4;
        float4 v;
        v.x = Q[(size_t)(d + 0) * 576 + q] * 0.125f;
        v.y = Q[(size_t)(d + 1) * 576 + q] * 0.125f;
        v.z = Q[(size_t)(d + 2) * 576 + q] * 0.125f;
        v.w = Q[(size_t)(d + 3) * 576 + q] * 0.125f;
        Q4[j] = v;
    }

    float4 O4[4];
    #pragma unroll
    for (int j = 0; j < 4; ++j) { O4[j].x = 0.f; O4[j].y = 0.f; O4[j].z = 0.f; O4[j].w = 0.f; }
    float l = 0.f;

    // staged registers for next tile
    float4 kr0, kr1, vr0, vr1;

    // prologue: load tile 0 and commit to buffer 0
    {
        const float* Ksrc = Kt + (size_t)lr * 64 + lc;
        const float* Vsrc = Vt + (size_t)lr * 64 + lc;
        kr0 = *(const float4*)(Ksrc + 0);
        kr1 = *(const float4*)(Ksrc + 4);
        vr0 = *(const float4*)(Vsrc + 0);
        vr1 = *(const float4*)(Vsrc + 4);
        *(float4*)&Ks_[0][lr][lc + 0] = kr0;
        *(float4*)&Ks_[0][lr][lc + 4] = kr1;
        *(float4*)&Vs_[0][lr][lc + 0] = vr0;
        *(float4*)&Vs_[0][lr][lc + 4] = vr1;
    }
    __syncthreads();

    const int NT = 576 / KVT;   // 18
    for (int tt = 0; tt < NT; ++tt) {
        const int cur = tt & 1;

        // issue next tile's global loads early (latency hides under compute)
        if (tt + 1 < NT) {
            const size_t row = (size_t)((tt + 1) * KVT + lr) * 64 + lc;
            const float* Ksrc = Kt + row;
            const float* Vsrc = Vt + row;
            kr0 = *(const float4*)(Ksrc + 0);
            kr1 = *(const float4*)(Ksrc + 4);
            vr0 = *(const float4*)(Vsrc + 0);
            vr1 = *(const float4*)(Vsrc + 4);
        }

        // compute tile from LDS
        #pragma unroll 8
        for (int kk = 0; kk < KVT; ++kk) {
            const float4* Kr = (const float4*)&Ks_[cur][kk][d0];
            float s0 = 0.f, s1 = 0.f, s2 = 0.f, s3 = 0.f;
            #pragma unroll
            for (int j = 0; j < 4; ++j) {
                float4 kj = Kr[j];
                s0 += Q4[j].x * kj.x;
                s1 += Q4[j].y * kj.y;
                s2 += Q4[j].z * kj.z;
                s3 += Q4[j].w * kj.w;
            }
            float sp = (s0 + s1) + (s2 + s3);
            sp += __shfl_xor(sp, 1);
            sp += __shfl_xor(sp, 2);
            float e = __expf(sp);
            l += e;

            const float4* Vr = (const float4*)&Vs_[cur][kk][d0];
            #pragma unroll
            for (int j = 0; j < 4; ++j) {
                float4 vj = Vr[j];
                O4[j].x += e * vj.x;
                O4[j].y += e * vj.y;
                O4[j].z += e * vj.z;
                O4[j].w += e * vj.w;
            }
        }

        if (tt + 1 < NT) {
            __syncthreads();   // everyone done reading buffer cur^1's old tile
            *(float4*)&Ks_[cur ^ 1][lr][lc + 0] = kr0;
            *(float4*)&Ks_[cur ^ 1][lr][lc + 4] = kr1;
            *(float4*)&Vs_[cur ^ 1][lr][lc + 0] = vr0;
            *(float4*)&Vs_[cur ^ 1][lr][lc + 4] = vr1;
            __syncthreads();   // next tile visible to all
        }
    }

    const float inv = 1.f / l;
    #pragma unroll
    for (int j = 0; j < 4; ++j) {
        const int d = d0 + j * 4;
        Q[(size_t)(d + 0) * 576 + q] = O4[j].x * inv;
        Q[(size_t)(d + 1) * 576 + q] = O4[j].y * inv;
        Q[(size_t)(d + 2) * 576 + q] = O4[j].z * inv;
        Q[(size_t)(d + 3) * 576 + q] = O4[j].w * inv;
    }
}

// ---------------------------------------------------------------------------
// Output projection, tiled GEMM, batched over (b,t) chunk (unchanged).
// ---------------------------------------------------------------------------
__global__ __launch_bounds__(256)
void proj_out_gemm(const float* __restrict__ ao,
                   const void* __restrict__ wo, const void* __restrict__ bo,
                   void* __restrict__ out, const int* __restrict__ flag, int bt_base)
{
    const int is_f32 = flag[0];
    const int btl = blockIdx.z;
    const int bt = bt_base + btl;
    const int b = bt >> 4, t = bt & 15;
    const float* A = ao + (size_t)btl * SLABF;

    const int o0 = blockIdx.y * 64;
    const int p0 = blockIdx.x * 64;
    const int tid = threadIdx.x;
    const int tx = tid & 15;
    const int ty = tid >> 4;

    __shared__ float  As[16][68];
    __shared__ float4 Bs[16][17];

    float acc[4][4];
    #pragma unroll
    for (int r = 0; r < 4; ++r) {
        float bb = in_read(bo, (size_t)(o0 + ty * 4 + r), is_f32);
        #pragma unroll
        for (int j = 0; j < 4; ++j) acc[r][j] = bb;
    }

    const int wo_l = tid >> 2;
    const int wc_l = (tid & 3) * 4;
    const int xc_l = ty;
    const int xp_l = tx * 4;

    for (int c0 = 0; c0 < 512; c0 += 16) {
        {
            size_t wbase = (size_t)(o0 + wo_l) * 512 + (size_t)(c0 + wc_l);
            #pragma unroll
            for (int i = 0; i < 4; ++i)
                As[wc_l + i][wo_l] = in_read(wo, wbase + i, is_f32);
        }
        Bs[xc_l][tx] = *(const float4*)&A[(size_t)(c0 + xc_l) * 576 + p0 + xp_l];
        __syncthreads();
        #pragma unroll
        for (int kk = 0; kk < 16; ++kk) {
            float4 bv = Bs[kk][tx];
            #pragma unroll
            for (int r = 0; r < 4; ++r) {
                float a = As[kk][ty * 4 + r];
                acc[r][0] += a * bv.x;
                acc[r][1] += a * bv.y;
                acc[r][2] += a * bv.z;
                acc[r][3] += a * bv.w;
            }
        }
        __syncthreads();
    }

    #pragma unroll
    for (int r = 0; r < 4; ++r) {
        const int o = o0 + ty * 4 + r;
        const size_t addr = ((size_t)(b * 512 + o) * 16 + t) * 576 + p0 + tx * 4;
        if (is_f32) {
            float4 st;
            st.x = acc[r][0]; st.y = acc[r][1]; st.z = acc[r][2]; st.w = acc[r][3];
            *(float4*)((float*)out + addr) = st;
        } else {
            unsigned int lo = (unsigned int)f2bf(acc[r][0]) |
                              ((unsigned int)f2bf(acc[r][1]) << 16);
            unsigned int hi = (unsigned int)f2bf(acc[r][2]) |
                              ((unsigned int)f2bf(acc[r][3]) << 16);
            uint2 st; st.x = lo; st.y = hi;
            *(uint2*)((ushort_t*)out + addr) = st;
        }
    }
}

extern "C" void kernel_launch(void* const* d_in, const int* in_sizes, int n_in,
                              void* d_out, int out_size, void* d_ws, size_t ws_size,
                              hipStream_t stream)
{
    (void)in_sizes; (void)n_in; (void)out_size;
    const void* x   = d_in[0];
    const void* wq  = d_in[1];
    const void* bq  = d_in[2];
    const void* wk  = d_in[3];
    const void* bk  = d_in[4];
    const void* wv  = d_in[5];
    const void* bv  = d_in[6];
    const void* wo  = d_in[7];
    const void* bo  = d_in[8];
    const void* pos = d_in[9];

    int*   flag  = (int*)d_ws;
    float* slab0 = (float*)((char*)d_ws + 256);

    const size_t per_bt = (size_t)3 * SLABF * sizeof(float);
    int chunk = 1;
    if (ws_size > 256 + per_bt) {
        size_t c = (ws_size - 256) / per_bt;
        chunk = (c > 32) ? 32 : (int)c;
    }
    if (chunk < 1) chunk = 1;

    detect_dtype<<<1, 256, 0, stream>>>((const ushort_t*)wq, flag);

    for (int bt0 = 0; bt0 < 32; bt0 += chunk) {
        const int nbt = (32 - bt0 < chunk) ? (32 - bt0) : chunk;
        float* qslab = slab0;
        float* kslab = qslab + (size_t)nbt * SLABF;
        float* vslab = kslab + (size_t)nbt * SLABF;

        proj_qkv_gemm<<<dim3(9, 8, nbt * 3), 256, 0, stream>>>(
            x, pos, wq, bq, wk, bk, wv, bv, qslab, kslab, vslab, flag, bt0);
        attn_lds<<<dim3(nbt * 72), 256, 0, stream>>>(qslab, kslab, vslab, nbt);
        proj_out_gemm<<<dim3(9, 8, nbt), 256, 0, stream>>>(
            qslab, wo, bo, d_out, flag, bt0);
    }
}

// Round 6
// 1380.702 us; speedup vs baseline: 47.4819x; 1.1671x over previous
//
#include <hip/hip_runtime.h>
#include <math.h>

typedef unsigned short ushort_t;
typedef short bf16x8 __attribute__((ext_vector_type(8)));
typedef float f32x4 __attribute__((ext_vector_type(4)));

#define SLABF (512 * 576)   /* floats per (b,t) scratch slab */
#define KVT   32            /* kv tile rows staged in LDS (attn) */
#define LDP   68            /* padded LDS row length (attn), floats */
#define APAD  40            /* mfma LDS row pad, halves (80 B, 16B-aligned) */
#define B2F   (3 * 16 * 512)  /* bias2 floats */

__device__ __forceinline__ float bf2f(ushort_t u) {
    union { unsigned int i; float f; } v;
    v.i = ((unsigned int)u) << 16;
    return v.f;
}
__device__ __forceinline__ ushort_t f2bf(float f) {
    union { float f; unsigned int i; } v;
    v.f = f;
    unsigned int r = v.i + 0x7FFFu + ((v.i >> 16) & 1u);
    return (ushort_t)(r >> 16);
}

// Read input element i from a buffer whose true dtype is selected by flag.
__device__ __forceinline__ float in_read(const void* p, size_t i, int is_f32) {
    if (is_f32) return ((const float*)p)[i];
    return bf2f(((const ushort_t*)p)[i]);
}

// ---------------------------------------------------------------------------
// Dtype probe (unchanged).
// ---------------------------------------------------------------------------
__global__ void detect_dtype(const ushort_t* wq_h, int* flag) {
    __shared__ int cnt;
    if (threadIdx.x == 0) cnt = 0;
    __syncthreads();
    int local = 0;
    for (int i = threadIdx.x; i < 4096; i += 256) {
        float v = bf2f(wq_h[i]);
        if (!(fabsf(v) < 1e6f)) local++;
    }
    atomicAdd(&cnt, local);
    __syncthreads();
    if (threadIdx.x == 0) flag[0] = (cnt > 10) ? 1 : 0;
}

// ---------------------------------------------------------------------------
// bias2[mode][t][o] = bias[o] + sum_c W[o][c] * pos[c][t]   (fp32, bf16 path
// only). Lets the MFMA kernel compute pure W*x: W(x+pos)+b = Wx + bias2.
// grid 48 = (mode,t); block 256; each thread 2 output rows.
// ---------------------------------------------------------------------------
__global__ __launch_bounds__(256)
void make_bias2(const ushort_t* __restrict__ w0, const ushort_t* __restrict__ b0,
                const ushort_t* __restrict__ w1, const ushort_t* __restrict__ b1,
                const ushort_t* __restrict__ w2, const ushort_t* __restrict__ b2,
                const ushort_t* __restrict__ pos, float* __restrict__ bias2,
                const int* __restrict__ flag)
{
    if (flag[0] != 0) return;   // fp32 fallback path doesn't use bias2
    const int mode = blockIdx.x / 16;
    const int t = blockIdx.x - mode * 16;
    const ushort_t* W; const ushort_t* bias;
    if (mode == 0)      { W = w0; bias = b0; }
    else if (mode == 1) { W = w1; bias = b1; }
    else                { W = w2; bias = b2; }

    __shared__ float posf[512];
    for (int c = threadIdx.x; c < 512; c += 256)
        posf[c] = bf2f(pos[c * 16 + t]);
    __syncthreads();

    #pragma unroll
    for (int half = 0; half < 2; ++half) {
        const int o = half * 256 + threadIdx.x;
        float a0 = 0.f, a1 = 0.f, a2 = 0.f, a3 = 0.f;
        const ushort_t* wr = W + (size_t)o * 512;
        for (int c = 0; c < 512; c += 8) {
            bf16x8 wv = *(const bf16x8*)(wr + c);
            a0 += bf2f((ushort_t)wv[0]) * posf[c + 0];
            a1 += bf2f((ushort_t)wv[1]) * posf[c + 1];
            a2 += bf2f((ushort_t)wv[2]) * posf[c + 2];
            a3 += bf2f((ushort_t)wv[3]) * posf[c + 3];
            a0 += bf2f((ushort_t)wv[4]) * posf[c + 4];
            a1 += bf2f((ushort_t)wv[5]) * posf[c + 5];
            a2 += bf2f((ushort_t)wv[6]) * posf[c + 6];
            a3 += bf2f((ushort_t)wv[7]) * posf[c + 7];
        }
        bias2[(size_t)(mode * 16 + t) * 512 + o] =
            bf2f(bias[o]) + ((a0 + a1) + (a2 + a3));
    }
}

// ---------------------------------------------------------------------------
// QKV projection via MFMA (bf16 inputs only; early-exits otherwise).
// out = W * x  + bias2[mode][t][:], batched over (b,t) chunk.
// Block: 4 waves; tile 256 o x 64 p; BK=32. Wave w owns o-range [w*64,w*64+64)
// as 4x4 fragments of mfma_f32_16x16x32_bf16.
// LDS: A = W tile [256][32] bf16 padded to 40 halves/row (16B-aligned b128
// fragment reads, ~2-way banks); B = x tile stored TRANSPOSED [p][c] so
// B-fragments (8 contiguous k at fixed p) are b128 reads.
// C/D layout (m89-verified): col = lane&15, row = (lane>>4)*4 + reg.
// K/V are stored to the transposed [h][p][64] slab layout directly.
// ---------------------------------------------------------------------------
__global__ __launch_bounds__(256)
void proj_qkv_mfma(const ushort_t* __restrict__ x,
                   const ushort_t* __restrict__ w0, const ushort_t* __restrict__ w1,
                   const ushort_t* __restrict__ w2,
                   const float* __restrict__ bias2,
                   float* __restrict__ qs, float* __restrict__ ks, float* __restrict__ vs,
                   const int* __restrict__ flag, int bt_base)
{
    if (flag[0] != 0) return;
    const int z = blockIdx.z;
    const int btl = z / 3;
    const int mode = z - btl * 3;
    const int bt = bt_base + btl;
    const int b = bt >> 4, t = bt & 15;

    const ushort_t* W = (mode == 0) ? w0 : (mode == 1) ? w1 : w2;
    float* out = ((mode == 0) ? qs : (mode == 1) ? ks : vs) + (size_t)btl * SLABF;
    const float* b2 = bias2 + (size_t)(mode * 16 + t) * 512;

    const int o0 = blockIdx.y * 256;   // 0 or 256
    const int p0 = blockIdx.x * 64;    // 9 tiles of 64
    const int tid = threadIdx.x;
    const int wid = tid >> 6;
    const int lane = tid & 63;
    const int lr = lane & 15;          // frag row (A) / col (B,D)
    const int lk = lane >> 4;          // k-chunk 0..3

    __shared__ ushort_t Ws_[256 * APAD];
    __shared__ ushort_t Xs_[64 * APAD];

    f32x4 acc[4][4];
    #pragma unroll
    for (int i = 0; i < 4; ++i)
        #pragma unroll
        for (int j = 0; j < 4; ++j) {
            f32x4 zz = {0.f, 0.f, 0.f, 0.f};
            acc[i][j] = zz;
        }

    const int bc = tid >> 3;           // B staging: c row 0..31
    const int bp = (tid & 7) * 8;      // B staging: p offset

    for (int c0 = 0; c0 < 512; c0 += 32) {
        // A stage: thread tid loads W row o0+tid, 32 halves (64 B)
        {
            const ushort_t* src = W + (size_t)(o0 + tid) * 512 + c0;
            #pragma unroll
            for (int ch = 0; ch < 4; ++ch) {
                bf16x8 v = *(const bf16x8*)(src + ch * 8);
                *(bf16x8*)(Ws_ + tid * APAD + ch * 8) = v;
            }
        }
        // B stage: row (c0+bc), cols p0+bp..+8, transposed into Xs_[p][c]
        {
            const ushort_t* src = x + ((size_t)(b * 512 + c0 + bc) * 16 + t) * 576
                                    + p0 + bp;
            bf16x8 v = *(const bf16x8*)src;
            #pragma unroll
            for (int e = 0; e < 8; ++e)
                Xs_[(bp + e) * APAD + bc] = (ushort_t)v[e];
        }
        __syncthreads();

        bf16x8 af[4], bfr[4];
        #pragma unroll
        for (int f = 0; f < 4; ++f)
            af[f] = *(const bf16x8*)(Ws_ + (wid * 64 + f * 16 + lr) * APAD + lk * 8);
        #pragma unroll
        for (int f = 0; f < 4; ++f)
            bfr[f] = *(const bf16x8*)(Xs_ + (f * 16 + lr) * APAD + lk * 8);

        #pragma unroll
        for (int fo = 0; fo < 4; ++fo)
            #pragma unroll
            for (int fp = 0; fp < 4; ++fp)
                acc[fo][fp] = __builtin_amdgcn_mfma_f32_16x16x32_bf16(
                    af[fo], bfr[fp], acc[fo][fp], 0, 0, 0);

        __syncthreads();
    }

    if (mode == 0) {
        // Q: [o][576]
        #pragma unroll
        for (int fo = 0; fo < 4; ++fo)
            #pragma unroll
            for (int reg = 0; reg < 4; ++reg) {
                const int o = o0 + wid * 64 + fo * 16 + lk * 4 + reg;
                const float bb = b2[o];
                #pragma unroll
                for (int fp = 0; fp < 4; ++fp)
                    out[(size_t)o * 576 + p0 + fp * 16 + lr] = acc[fo][fp][reg] + bb;
            }
    } else {
        // K/V: [h][p][64]
        #pragma unroll
        for (int fo = 0; fo < 4; ++fo)
            #pragma unroll
            for (int reg = 0; reg < 4; ++reg) {
                const int o = o0 + wid * 64 + fo * 16 + lk * 4 + reg;
                const float bb = b2[o];
                float* ob = out + (size_t)(o >> 6) * (576 * 64) + (o & 63);
                #pragma unroll
                for (int fp = 0; fp < 4; ++fp)
                    ob[(size_t)(p0 + fp * 16 + lr) * 64] = acc[fo][fp][reg] + bb;
            }
    }
}

// ---------------------------------------------------------------------------
// Vector QKV projection — fp32 fallback only (early-exits on bf16).
// ---------------------------------------------------------------------------
__global__ __launch_bounds__(256)
void proj_qkv_gemm(const void* __restrict__ x, const void* __restrict__ pos,
                   const void* __restrict__ w0, const void* __restrict__ b0,
                   const void* __restrict__ w1, const void* __restrict__ b1,
                   const void* __restrict__ w2, const void* __restrict__ b2,
                   float* __restrict__ qs, float* __restrict__ ks, float* __restrict__ vs,
                   const int* __restrict__ flag, int bt_base)
{
    const int is_f32 = flag[0];
    if (is_f32 == 0) return;   // bf16 handled by MFMA kernel
    const int z = blockIdx.z;
    const int btl = z / 3;
    const int mode = z - btl * 3;
    const int bt = bt_base + btl;
    const int b = bt >> 4, t = bt & 15;

    const void* W; const void* bias; float* out;
    if (mode == 0)      { W = w0; bias = b0; out = qs; }
    else if (mode == 1) { W = w1; bias = b1; out = ks; }
    else                { W = w2; bias = b2; out = vs; }
    out += (size_t)btl * SLABF;

    const int o0 = blockIdx.y * 64;
    const int p0 = blockIdx.x * 64;
    const int tid = threadIdx.x;
    const int tx = tid & 15;
    const int ty = tid >> 4;

    __shared__ float  As[16][68];
    __shared__ float4 Bs[16][17];

    float acc[4][4];
    #pragma unroll
    for (int r = 0; r < 4; ++r) {
        float bb = in_read(bias, (size_t)(o0 + ty * 4 + r), is_f32);
        #pragma unroll
        for (int j = 0; j < 4; ++j) acc[r][j] = bb;
    }

    const int wo_l = tid >> 2;
    const int wc_l = (tid & 3) * 4;
    const int xc_l = ty;
    const int xp_l = tx * 4;

    for (int c0 = 0; c0 < 512; c0 += 16) {
        {
            size_t wbase = (size_t)(o0 + wo_l) * 512 + (size_t)(c0 + wc_l);
            #pragma unroll
            for (int i = 0; i < 4; ++i)
                As[wc_l + i][wo_l] = in_read(W, wbase + i, is_f32);
        }
        {
            float pv = in_read(pos, (size_t)(c0 + xc_l) * 16 + t, is_f32);
            size_t xbase = ((size_t)(b * 512 + c0 + xc_l) * 16 + t) * 576 + p0 + xp_l;
            float4 xv;
            xv.x = in_read(x, xbase + 0, is_f32) + pv;
            xv.y = in_read(x, xbase + 1, is_f32) + pv;
            xv.z = in_read(x, xbase + 2, is_f32) + pv;
            xv.w = in_read(x, xbase + 3, is_f32) + pv;
            Bs[xc_l][tx] = xv;
        }
        __syncthreads();
        #pragma unroll
        for (int kk = 0; kk < 16; ++kk) {
            float4 bv = Bs[kk][tx];
            #pragma unroll
            for (int r = 0; r < 4; ++r) {
                float a = As[kk][ty * 4 + r];
                acc[r][0] += a * bv.x;
                acc[r][1] += a * bv.y;
                acc[r][2] += a * bv.z;
                acc[r][3] += a * bv.w;
            }
        }
        __syncthreads();
    }

    if (mode == 0) {
        #pragma unroll
        for (int r = 0; r < 4; ++r) {
            float4 st;
            st.x = acc[r][0]; st.y = acc[r][1]; st.z = acc[r][2]; st.w = acc[r][3];
            *(float4*)&out[(size_t)(o0 + ty * 4 + r) * 576 + p0 + tx * 4] = st;
        }
    } else {
        #pragma unroll
        for (int j = 0; j < 4; ++j) {
            float4 st;
            st.x = acc[0][j]; st.y = acc[1][j]; st.z = acc[2][j]; st.w = acc[3][j];
            *(float4*)&out[(size_t)o0 * 576 +
                           (size_t)(p0 + tx * 4 + j) * 64 + ty * 4] = st;
        }
    }
}

// ---------------------------------------------------------------------------
// Attention (unchanged from round 5): 4-lane d-split, LDS double-buffered K/V.
// ---------------------------------------------------------------------------
__global__ __launch_bounds__(256)
void attn_lds(float* __restrict__ qs, const float* __restrict__ ks,
              const float* __restrict__ vs, int nbt)
{
    const int L = blockIdx.x;
    const int w = (L & 7) * (nbt * 9) + (L >> 3);
    const int pair = w / 9;
    const int qt = w - pair * 9;
    const int btl = pair >> 3;
    const int h = pair & 7;

    const int tid = threadIdx.x;
    const int ql = tid >> 2;
    const int dg = tid & 3;
    const int d0 = dg * 16;
    const int q = qt * 64 + ql;

    const size_t slab = (size_t)btl * SLABF;
    float* __restrict__ Q = qs + slab + (size_t)(h * 64) * 576;
    const float* __restrict__ Kt = ks + slab + (size_t)h * (576 * 64);
    const float* __restrict__ Vt = vs + slab + (size_t)h * (576 * 64);

    __shared__ float Ks_[2][KVT][LDP];
    __shared__ float Vs_[2][KVT][LDP];

    const int lr = tid >> 3;
    const int lc = (tid & 7) * 8;

    float4 Q4[4];
    #pragma unroll
    for (int j = 0; j < 4; ++j) {
        const int d = d0 + j * 4;
        float4 v;
        v.x = Q[(size_t)(d + 0) * 576 + q] * 0.125f;
        v.y = Q[(size_t)(d + 1) * 576 + q] * 0.125f;
        v.z = Q[(size_t)(d + 2) * 576 + q] * 0.125f;
        v.w = Q[(size_t)(d + 3) * 576 + q] * 0.125f;
        Q4[j] = v;
    }

    float4 O4[4];
    #pragma unroll
    for (int j = 0; j < 4; ++j) { O4[j].x = 0.f; O4[j].y = 0.f; O4[j].z = 0.f; O4[j].w = 0.f; }
    float l = 0.f;

    float4 kr0, kr1, vr0, vr1;
    {
        const float* Ksrc = Kt + (size_t)lr * 64 + lc;
        const float* Vsrc = Vt + (size_t)lr * 64 + lc;
        kr0 = *(const float4*)(Ksrc + 0);
        kr1 = *(const float4*)(Ksrc + 4);
        vr0 = *(const float4*)(Vsrc + 0);
        vr1 = *(const float4*)(Vsrc + 4);
        *(float4*)&Ks_[0][lr][lc + 0] = kr0;
        *(float4*)&Ks_[0][lr][lc + 4] = kr1;
        *(float4*)&Vs_[0][lr][lc + 0] = vr0;
        *(float4*)&Vs_[0][lr][lc + 4] = vr1;
    }
    __syncthreads();

    const int NT = 576 / KVT;
    for (int tt = 0; tt < NT; ++tt) {
        const int cur = tt & 1;

        if (tt + 1 < NT) {
            const size_t row = (size_t)((tt + 1) * KVT + lr) * 64 + lc;
            const float* Ksrc = Kt + row;
            const float* Vsrc = Vt + row;
            kr0 = *(const float4*)(Ksrc + 0);
            kr1 = *(const float4*)(Ksrc + 4);
            vr0 = *(const float4*)(Vsrc + 0);
            vr1 = *(const float4*)(Vsrc + 4);
        }

        #pragma unroll 8
        for (int kk = 0; kk < KVT; ++kk) {
            const float4* Kr = (const float4*)&Ks_[cur][kk][d0];
            float s0 = 0.f, s1 = 0.f, s2 = 0.f, s3 = 0.f;
            #pragma unroll
            for (int j = 0; j < 4; ++j) {
                float4 kj = Kr[j];
                s0 += Q4[j].x * kj.x;
                s1 += Q4[j].y * kj.y;
                s2 += Q4[j].z * kj.z;
                s3 += Q4[j].w * kj.w;
            }
            float sp = (s0 + s1) + (s2 + s3);
            sp += __shfl_xor(sp, 1);
            sp += __shfl_xor(sp, 2);
            float e = __expf(sp);
            l += e;

            const float4* Vr = (const float4*)&Vs_[cur][kk][d0];
            #pragma unroll
            for (int j = 0; j < 4; ++j) {
                float4 vj = Vr[j];
                O4[j].x += e * vj.x;
                O4[j].y += e * vj.y;
                O4[j].z += e * vj.z;
                O4[j].w += e * vj.w;
            }
        }

        if (tt + 1 < NT) {
            __syncthreads();
            *(float4*)&Ks_[cur ^ 1][lr][lc + 0] = kr0;
            *(float4*)&Ks_[cur ^ 1][lr][lc + 4] = kr1;
            *(float4*)&Vs_[cur ^ 1][lr][lc + 0] = vr0;
            *(float4*)&Vs_[cur ^ 1][lr][lc + 4] = vr1;
            __syncthreads();
        }
    }

    const float inv = 1.f / l;
    #pragma unroll
    for (int j = 0; j < 4; ++j) {
        const int d = d0 + j * 4;
        Q[(size_t)(d + 0) * 576 + q] = O4[j].x * inv;
        Q[(size_t)(d + 1) * 576 + q] = O4[j].y * inv;
        Q[(size_t)(d + 2) * 576 + q] = O4[j].z * inv;
        Q[(size_t)(d + 3) * 576 + q] = O4[j].w * inv;
    }
}

// ---------------------------------------------------------------------------
// Output projection, tiled GEMM (unchanged).
// ---------------------------------------------------------------------------
__global__ __launch_bounds__(256)
void proj_out_gemm(const float* __restrict__ ao,
                   const void* __restrict__ wo, const void* __restrict__ bo,
                   void* __restrict__ out, const int* __restrict__ flag, int bt_base)
{
    const int is_f32 = flag[0];
    const int btl = blockIdx.z;
    const int bt = bt_base + btl;
    const int b = bt >> 4, t = bt & 15;
    const float* A = ao + (size_t)btl * SLABF;

    const int o0 = blockIdx.y * 64;
    const int p0 = blockIdx.x * 64;
    const int tid = threadIdx.x;
    const int tx = tid & 15;
    const int ty = tid >> 4;

    __shared__ float  As[16][68];
    __shared__ float4 Bs[16][17];

    float acc[4][4];
    #pragma unroll
    for (int r = 0; r < 4; ++r) {
        float bb = in_read(bo, (size_t)(o0 + ty * 4 + r), is_f32);
        #pragma unroll
        for (int j = 0; j < 4; ++j) acc[r][j] = bb;
    }

    const int wo_l = tid >> 2;
    const int wc_l = (tid & 3) * 4;
    const int xc_l = ty;
    const int xp_l = tx * 4;

    for (int c0 = 0; c0 < 512; c0 += 16) {
        {
            size_t wbase = (size_t)(o0 + wo_l) * 512 + (size_t)(c0 + wc_l);
            #pragma unroll
            for (int i = 0; i < 4; ++i)
                As[wc_l + i][wo_l] = in_read(wo, wbase + i, is_f32);
        }
        Bs[xc_l][tx] = *(const float4*)&A[(size_t)(c0 + xc_l) * 576 + p0 + xp_l];
        __syncthreads();
        #pragma unroll
        for (int kk = 0; kk < 16; ++kk) {
            float4 bv = Bs[kk][tx];
            #pragma unroll
            for (int r = 0; r < 4; ++r) {
                float a = As[kk][ty * 4 + r];
                acc[r][0] += a * bv.x;
                acc[r][1] += a * bv.y;
                acc[r][2] += a * bv.z;
                acc[r][3] += a * bv.w;
            }
        }
        __syncthreads();
    }

    #pragma unroll
    for (int r = 0; r < 4; ++r) {
        const int o = o0 + ty * 4 + r;
        const size_t addr = ((size_t)(b * 512 + o) * 16 + t) * 576 + p0 + tx * 4;
        if (is_f32) {
            float4 st;
            st.x = acc[r][0]; st.y = acc[r][1]; st.z = acc[r][2]; st.w = acc[r][3];
            *(float4*)((float*)out + addr) = st;
        } else {
            unsigned int lo = (unsigned int)f2bf(acc[r][0]) |
                              ((unsigned int)f2bf(acc[r][1]) << 16);
            unsigned int hi = (unsigned int)f2bf(acc[r][2]) |
                              ((unsigned int)f2bf(acc[r][3]) << 16);
            uint2 st; st.x = lo; st.y = hi;
            *(uint2*)((ushort_t*)out + addr) = st;
        }
    }
}

extern "C" void kernel_launch(void* const* d_in, const int* in_sizes, int n_in,
                              void* d_out, int out_size, void* d_ws, size_t ws_size,
                              hipStream_t stream)
{
    (void)in_sizes; (void)n_in; (void)out_size;
    const void* x   = d_in[0];
    const void* wq  = d_in[1];
    const void* bq  = d_in[2];
    const void* wk  = d_in[3];
    const void* bk  = d_in[4];
    const void* wv  = d_in[5];
    const void* bv  = d_in[6];
    const void* wo  = d_in[7];
    const void* bo  = d_in[8];
    const void* pos = d_in[9];

    int*   flag   = (int*)d_ws;
    float* bias2  = (float*)((char*)d_ws + 256);
    float* slab0  = (float*)((char*)d_ws + 256 + B2F * sizeof(float));
    const size_t head_bytes = 256 + B2F * sizeof(float);

    const size_t per_bt = (size_t)3 * SLABF * sizeof(float);
    int chunk = 1;
    if (ws_size > head_bytes + per_bt) {
        size_t c = (ws_size - head_bytes) / per_bt;
        chunk = (c > 32) ? 32 : (int)c;
    }
    if (chunk < 1) chunk = 1;

    detect_dtype<<<1, 256, 0, stream>>>((const ushort_t*)wq, flag);
    make_bias2<<<48, 256, 0, stream>>>(
        (const ushort_t*)wq, (const ushort_t*)bq,
        (const ushort_t*)wk, (const ushort_t*)bk,
        (const ushort_t*)wv, (const ushort_t*)bv,
        (const ushort_t*)pos, bias2, flag);

    for (int bt0 = 0; bt0 < 32; bt0 += chunk) {
        const int nbt = (32 - bt0 < chunk) ? (32 - bt0) : chunk;
        float* qslab = slab0;
        float* kslab = qslab + (size_t)nbt * SLABF;
        float* vslab = kslab + (size_t)nbt * SLABF;

        proj_qkv_mfma<<<dim3(9, 2, nbt * 3), 256, 0, stream>>>(
            (const ushort_t*)x, (const ushort_t*)wq, (const ushort_t*)wk,
            (const ushort_t*)wv, bias2, qslab, kslab, vslab, flag, bt0);
        proj_qkv_gemm<<<dim3(9, 8, nbt * 3), 256, 0, stream>>>(
            x, pos, wq, bq, wk, bk, wv, bv, qslab, kslab, vslab, flag, bt0);
        attn_lds<<<dim3(nbt * 72), 256, 0, stream>>>(qslab, kslab, vslab, nbt);
        proj_out_gemm<<<dim3(9, 8, nbt), 256, 0, stream>>>(
            qslab, wo, bo, d_out, flag, bt0);
    }
}

// Round 7
// 722.350 us; speedup vs baseline: 90.7571x; 1.9114x over previous
//
#include <hip/hip_runtime.h>
#include <math.h>

typedef unsigned short ushort_t;
typedef short bf16x8 __attribute__((ext_vector_type(8)));
typedef float f32x4 __attribute__((ext_vector_type(4)));

#define SLABF (512 * 576)     /* floats per (b,t) slab; also ushorts per bf16 plane */
#define APAD  40              /* proj mfma LDS row pad, halves */
#define B2F   (3 * 16 * 512)  /* bias2 floats */

__device__ __forceinline__ float bf2f(ushort_t u) {
    union { unsigned int i; float f; } v;
    v.i = ((unsigned int)u) << 16;
    return v.f;
}
__device__ __forceinline__ ushort_t f2bf(float f) {
    union { float f; unsigned int i; } v;
    v.f = f;
    unsigned int r = v.i + 0x7FFFu + ((v.i >> 16) & 1u);
    return (ushort_t)(r >> 16);
}
// hi/lo split: x ~= bf2f(hi) + bf2f(lo), residual ~ x*2^-17
__device__ __forceinline__ void split_hl(float x, ushort_t& hi, ushort_t& lo) {
    hi = f2bf(x);
    lo = f2bf(x - bf2f(hi));
}

__device__ __forceinline__ float in_read(const void* p, size_t i, int is_f32) {
    if (is_f32) return ((const float*)p)[i];
    return bf2f(((const ushort_t*)p)[i]);
}

// ---------------------------------------------------------------------------
// Dtype probe (unchanged).
// ---------------------------------------------------------------------------
__global__ void detect_dtype(const ushort_t* wq_h, int* flag) {
    __shared__ int cnt;
    if (threadIdx.x == 0) cnt = 0;
    __syncthreads();
    int local = 0;
    for (int i = threadIdx.x; i < 4096; i += 256) {
        float v = bf2f(wq_h[i]);
        if (!(fabsf(v) < 1e6f)) local++;
    }
    atomicAdd(&cnt, local);
    __syncthreads();
    if (threadIdx.x == 0) flag[0] = (cnt > 10) ? 1 : 0;
}

// ---------------------------------------------------------------------------
// bias2[mode][t][o] = bias[o] + sum_c W[o][c] * pos[c][t]  (bf16 path only).
// ---------------------------------------------------------------------------
__global__ __launch_bounds__(256)
void make_bias2(const ushort_t* __restrict__ w0, const ushort_t* __restrict__ b0,
                const ushort_t* __restrict__ w1, const ushort_t* __restrict__ b1,
                const ushort_t* __restrict__ w2, const ushort_t* __restrict__ b2,
                const ushort_t* __restrict__ pos, float* __restrict__ bias2,
                const int* __restrict__ flag)
{
    if (flag[0] != 0) return;
    const int mode = blockIdx.x / 16;
    const int t = blockIdx.x - mode * 16;
    const ushort_t* W; const ushort_t* bias;
    if (mode == 0)      { W = w0; bias = b0; }
    else if (mode == 1) { W = w1; bias = b1; }
    else                { W = w2; bias = b2; }

    __shared__ float posf[512];
    for (int c = threadIdx.x; c < 512; c += 256)
        posf[c] = bf2f(pos[c * 16 + t]);
    __syncthreads();

    #pragma unroll
    for (int half = 0; half < 2; ++half) {
        const int o = half * 256 + threadIdx.x;
        float a0 = 0.f, a1 = 0.f, a2 = 0.f, a3 = 0.f;
        const ushort_t* wr = W + (size_t)o * 512;
        for (int c = 0; c < 512; c += 8) {
            bf16x8 wv = *(const bf16x8*)(wr + c);
            a0 += bf2f((ushort_t)wv[0]) * posf[c + 0];
            a1 += bf2f((ushort_t)wv[1]) * posf[c + 1];
            a2 += bf2f((ushort_t)wv[2]) * posf[c + 2];
            a3 += bf2f((ushort_t)wv[3]) * posf[c + 3];
            a0 += bf2f((ushort_t)wv[4]) * posf[c + 4];
            a1 += bf2f((ushort_t)wv[5]) * posf[c + 5];
            a2 += bf2f((ushort_t)wv[6]) * posf[c + 6];
            a3 += bf2f((ushort_t)wv[7]) * posf[c + 7];
        }
        bias2[(size_t)(mode * 16 + t) * 512 + o] =
            bf2f(bias[o]) + ((a0 + a1) + (a2 + a3));
    }
}

// ---------------------------------------------------------------------------
// QKV projection via MFMA (bf16 path).
// Slab layouts produced:
//   Q: fp32 [h][d][576]
//   K: bf16 hi/lo planes, each [h][kv=576][d=64]   (klo = khi + SLABF ushorts)
//   V: bf16 hi/lo planes, each [h][d=64][kv=576]
// Fragment patterns identical to round-6 hardware-verified kernel.
// ---------------------------------------------------------------------------
__global__ __launch_bounds__(256)
void proj_qkv_mfma(const ushort_t* __restrict__ x,
                   const ushort_t* __restrict__ w0, const ushort_t* __restrict__ w1,
                   const ushort_t* __restrict__ w2,
                   const float* __restrict__ bias2,
                   float* __restrict__ qs, float* __restrict__ ks, float* __restrict__ vs,
                   const int* __restrict__ flag, int bt_base)
{
    if (flag[0] != 0) return;
    const int z = blockIdx.z;
    const int btl = z / 3;
    const int mode = z - btl * 3;
    const int bt = bt_base + btl;
    const int b = bt >> 4, t = bt & 15;

    const ushort_t* W = (mode == 0) ? w0 : (mode == 1) ? w1 : w2;
    float* out = ((mode == 0) ? qs : (mode == 1) ? ks : vs) + (size_t)btl * SLABF;
    const float* b2 = bias2 + (size_t)(mode * 16 + t) * 512;

    const int o0 = blockIdx.y * 256;
    const int p0 = blockIdx.x * 64;
    const int tid = threadIdx.x;
    const int wid = tid >> 6;
    const int lane = tid & 63;
    const int lr = lane & 15;
    const int lk = lane >> 4;

    __shared__ ushort_t Ws_[256 * APAD];
    __shared__ ushort_t Xs_[64 * APAD];

    f32x4 acc[4][4];
    #pragma unroll
    for (int i = 0; i < 4; ++i)
        #pragma unroll
        for (int j = 0; j < 4; ++j) {
            f32x4 zz = {0.f, 0.f, 0.f, 0.f};
            acc[i][j] = zz;
        }

    const int bc = tid >> 3;
    const int bp = (tid & 7) * 8;

    for (int c0 = 0; c0 < 512; c0 += 32) {
        {
            const ushort_t* src = W + (size_t)(o0 + tid) * 512 + c0;
            #pragma unroll
            for (int ch = 0; ch < 4; ++ch) {
                bf16x8 v = *(const bf16x8*)(src + ch * 8);
                *(bf16x8*)(Ws_ + tid * APAD + ch * 8) = v;
            }
        }
        {
            const ushort_t* src = x + ((size_t)(b * 512 + c0 + bc) * 16 + t) * 576
                                    + p0 + bp;
            bf16x8 v = *(const bf16x8*)src;
            #pragma unroll
            for (int e = 0; e < 8; ++e)
                Xs_[(bp + e) * APAD + bc] = (ushort_t)v[e];
        }
        __syncthreads();

        bf16x8 af[4], bfr[4];
        #pragma unroll
        for (int f = 0; f < 4; ++f)
            af[f] = *(const bf16x8*)(Ws_ + (wid * 64 + f * 16 + lr) * APAD + lk * 8);
        #pragma unroll
        for (int f = 0; f < 4; ++f)
            bfr[f] = *(const bf16x8*)(Xs_ + (f * 16 + lr) * APAD + lk * 8);

        #pragma unroll
        for (int fo = 0; fo < 4; ++fo)
            #pragma unroll
            for (int fp = 0; fp < 4; ++fp)
                acc[fo][fp] = __builtin_amdgcn_mfma_f32_16x16x32_bf16(
                    af[fo], bfr[fp], acc[fo][fp], 0, 0, 0);

        __syncthreads();
    }

    if (mode == 0) {
        // Q: fp32 [o][576]
        #pragma unroll
        for (int fo = 0; fo < 4; ++fo)
            #pragma unroll
            for (int reg = 0; reg < 4; ++reg) {
                const int o = o0 + wid * 64 + fo * 16 + lk * 4 + reg;
                const float bb = b2[o];
                #pragma unroll
                for (int fp = 0; fp < 4; ++fp)
                    out[(size_t)o * 576 + p0 + fp * 16 + lr] = acc[fo][fp][reg] + bb;
            }
    } else if (mode == 1) {
        // K planes: [h][kv][64] hi/lo
        ushort_t* khi = (ushort_t*)out;
        ushort_t* klo = khi + SLABF;
        #pragma unroll
        for (int fo = 0; fo < 4; ++fo)
            #pragma unroll
            for (int reg = 0; reg < 4; ++reg) {
                const int o = o0 + wid * 64 + fo * 16 + lk * 4 + reg;
                const float bb = b2[o];
                const size_t base = (size_t)(o >> 6) * (576 * 64) + (o & 63);
                #pragma unroll
                for (int fp = 0; fp < 4; ++fp) {
                    float v = acc[fo][fp][reg] + bb;
                    ushort_t hi, lo; split_hl(v, hi, lo);
                    const size_t off = base + (size_t)(p0 + fp * 16 + lr) * 64;
                    khi[off] = hi; klo[off] = lo;
                }
            }
    } else {
        // V planes: [h][d][576] hi/lo
        ushort_t* vhi = (ushort_t*)out;
        ushort_t* vlo = vhi + SLABF;
        #pragma unroll
        for (int fo = 0; fo < 4; ++fo)
            #pragma unroll
            for (int reg = 0; reg < 4; ++reg) {
                const int o = o0 + wid * 64 + fo * 16 + lk * 4 + reg;
                const float bb = b2[o];
                #pragma unroll
                for (int fp = 0; fp < 4; ++fp) {
                    float v = acc[fo][fp][reg] + bb;
                    ushort_t hi, lo; split_hl(v, hi, lo);
                    const size_t off = (size_t)o * 576 + p0 + fp * 16 + lr;
                    vhi[off] = hi; vlo[off] = lo;
                }
            }
    }
}

// ---------------------------------------------------------------------------
// Vector QKV projection — fp32 fallback only. Produces the same slab layouts
// (Q fp32; K/V hi/lo bf16 planes).
// ---------------------------------------------------------------------------
__global__ __launch_bounds__(256)
void proj_qkv_gemm(const void* __restrict__ x, const void* __restrict__ pos,
                   const void* __restrict__ w0, const void* __restrict__ b0,
                   const void* __restrict__ w1, const void* __restrict__ b1,
                   const void* __restrict__ w2, const void* __restrict__ b2,
                   float* __restrict__ qs, float* __restrict__ ks, float* __restrict__ vs,
                   const int* __restrict__ flag, int bt_base)
{
    const int is_f32 = flag[0];
    if (is_f32 == 0) return;
    const int z = blockIdx.z;
    const int btl = z / 3;
    const int mode = z - btl * 3;
    const int bt = bt_base + btl;
    const int b = bt >> 4, t = bt & 15;

    const void* W; const void* bias; float* out;
    if (mode == 0)      { W = w0; bias = b0; out = qs; }
    else if (mode == 1) { W = w1; bias = b1; out = ks; }
    else                { W = w2; bias = b2; out = vs; }
    out += (size_t)btl * SLABF;

    const int o0 = blockIdx.y * 64;
    const int p0 = blockIdx.x * 64;
    const int tid = threadIdx.x;
    const int tx = tid & 15;
    const int ty = tid >> 4;

    __shared__ float  As[16][68];
    __shared__ float4 Bs[16][17];

    float acc[4][4];
    #pragma unroll
    for (int r = 0; r < 4; ++r) {
        float bb = in_read(bias, (size_t)(o0 + ty * 4 + r), is_f32);
        #pragma unroll
        for (int j = 0; j < 4; ++j) acc[r][j] = bb;
    }

    const int wo_l = tid >> 2;
    const int wc_l = (tid & 3) * 4;
    const int xc_l = ty;
    const int xp_l = tx * 4;

    for (int c0 = 0; c0 < 512; c0 += 16) {
        {
            size_t wbase = (size_t)(o0 + wo_l) * 512 + (size_t)(c0 + wc_l);
            #pragma unroll
            for (int i = 0; i < 4; ++i)
                As[wc_l + i][wo_l] = in_read(W, wbase + i, is_f32);
        }
        {
            float pv = in_read(pos, (size_t)(c0 + xc_l) * 16 + t, is_f32);
            size_t xbase = ((size_t)(b * 512 + c0 + xc_l) * 16 + t) * 576 + p0 + xp_l;
            float4 xv;
            xv.x = in_read(x, xbase + 0, is_f32) + pv;
            xv.y = in_read(x, xbase + 1, is_f32) + pv;
            xv.z = in_read(x, xbase + 2, is_f32) + pv;
            xv.w = in_read(x, xbase + 3, is_f32) + pv;
            Bs[xc_l][tx] = xv;
        }
        __syncthreads();
        #pragma unroll
        for (int kk = 0; kk < 16; ++kk) {
            float4 bv = Bs[kk][tx];
            #pragma unroll
            for (int r = 0; r < 4; ++r) {
                float a = As[kk][ty * 4 + r];
                acc[r][0] += a * bv.x;
                acc[r][1] += a * bv.y;
                acc[r][2] += a * bv.z;
                acc[r][3] += a * bv.w;
            }
        }
        __syncthreads();
    }

    if (mode == 0) {
        #pragma unroll
        for (int r = 0; r < 4; ++r) {
            float4 st;
            st.x = acc[r][0]; st.y = acc[r][1]; st.z = acc[r][2]; st.w = acc[r][3];
            *(float4*)&out[(size_t)(o0 + ty * 4 + r) * 576 + p0 + tx * 4] = st;
        }
    } else if (mode == 1) {
        ushort_t* khi = (ushort_t*)out;
        ushort_t* klo = khi + SLABF;
        #pragma unroll
        for (int j = 0; j < 4; ++j) {
            ushort4 sh, sl;
            split_hl(acc[0][j], sh.x, sl.x);
            split_hl(acc[1][j], sh.y, sl.y);
            split_hl(acc[2][j], sh.z, sl.z);
            split_hl(acc[3][j], sh.w, sl.w);
            const size_t off = (size_t)o0 * 576 + (size_t)(p0 + tx * 4 + j) * 64 + ty * 4;
            *(ushort4*)&khi[off] = sh;
            *(ushort4*)&klo[off] = sl;
        }
    } else {
        ushort_t* vhi = (ushort_t*)out;
        ushort_t* vlo = vhi + SLABF;
        #pragma unroll
        for (int r = 0; r < 4; ++r) {
            ushort4 sh, sl;
            split_hl(acc[r][0], sh.x, sl.x);
            split_hl(acc[r][1], sh.y, sl.y);
            split_hl(acc[r][2], sh.z, sl.z);
            split_hl(acc[r][3], sh.w, sl.w);
            const size_t off = (size_t)(o0 + ty * 4 + r) * 576 + p0 + tx * 4;
            *(ushort4*)&vhi[off] = sh;
            *(ushort4*)&vlo[off] = sl;
        }
    }
}

// ---------------------------------------------------------------------------
// Attention via MFMA, hi/lo bf16 3-pass products (fp32-class accuracy).
// Block = 256 thr = 4 waves; one (btl, h, 64-q tile); wave w owns 16 q rows.
// Per 32-kv tile:
//   S^T = K·Q^T  (A=K [kv][d] LDS, B=Q [q][d] LDS; D: col=q=lr, row=kv)
//   exp in regs, P packed hi/lo into per-wave LDS [q][kv]
//   O += P·V     (A=P [q][kv] LDS, B=V^T [d][kv] LDS; D: row=q, col=d)
// Online denominator lsum per lane, reduced via shfl_xor(16,32) at end.
// AO (= O / l) overwrites the Q slab in [c][p] layout for proj_out.
// ---------------------------------------------------------------------------
__global__ __launch_bounds__(256)
void attn_mfma(float* __restrict__ qs, const float* __restrict__ ks,
               const float* __restrict__ vs, int nbt)
{
    const int L = blockIdx.x;
    const int w9 = (L & 7) * (nbt * 9) + (L >> 3);
    const int pair = w9 / 9;
    const int qt = w9 - pair * 9;
    const int btl = pair >> 3;
    const int h = pair & 7;

    const int tid = threadIdx.x;
    const int wid = tid >> 6;
    const int lane = tid & 63;
    const int lr = lane & 15;
    const int lk = lane >> 4;

    const size_t slab = (size_t)btl * SLABF;
    float* __restrict__ Qs = qs + slab + (size_t)(h * 64) * 576;  // fp32 [d][576]; AO out
    const ushort_t* kbase = (const ushort_t*)(ks + slab);
    const ushort_t* Khi_g = kbase + (size_t)h * (576 * 64);           // [kv][64]
    const ushort_t* Klo_g = kbase + SLABF + (size_t)h * (576 * 64);
    const ushort_t* vbase = (const ushort_t*)(vs + slab);
    const ushort_t* Vhi_g = vbase + (size_t)h * (64 * 576);           // [d][576]
    const ushort_t* Vlo_g = vbase + SLABF + (size_t)h * (64 * 576);

    __shared__ ushort_t Kh[32][72], Kl[32][72];   // [kv][d], 144B rows
    __shared__ ushort_t Vh[64][40], Vl[64][40];   // [d][kv], 80B rows
    __shared__ ushort_t Qh[64][72], Ql[64][72];   // [q][d]
    __shared__ ushort_t Ph[4][16][40], Pl[4][16][40]; // per-wave [q][kv]
    __shared__ float Lrow[4][16];

    // ---- stage Q (once): fp32 -> scaled hi/lo bf16, transposed to [q][d]
    {
        const int q = tid & 63, dd0 = (tid >> 6) * 16;
        const int qg = qt * 64 + q;
        #pragma unroll
        for (int i = 0; i < 16; ++i) {
            float v = Qs[(size_t)(dd0 + i) * 576 + qg] * 0.125f;
            ushort_t hi, lo; split_hl(v, hi, lo);
            Qh[q][dd0 + i] = hi; Ql[q][dd0 + i] = lo;
        }
    }

    // K/V tile staging coords (pure bf16 copies)
    const int skv = tid >> 3, sd = (tid & 7) * 8;   // K: [skv][sd..+8]
    const int svd = tid >> 2, skb = (tid & 3) * 8;  // V: [svd][skb..+8]
    uint4 kh_r, kl_r, vh_r, vl_r;

    {   // tile 0
        const size_t ko = (size_t)skv * 64 + sd;
        kh_r = *(const uint4*)(Khi_g + ko);
        kl_r = *(const uint4*)(Klo_g + ko);
        const size_t vo = (size_t)svd * 576 + skb;
        vh_r = *(const uint4*)(Vhi_g + vo);
        vl_r = *(const uint4*)(Vlo_g + vo);
        *(uint4*)&Kh[skv][sd] = kh_r; *(uint4*)&Kl[skv][sd] = kl_r;
        *(uint4*)&Vh[svd][skb] = vh_r; *(uint4*)&Vl[svd][skb] = vl_r;
    }
    __syncthreads();

    // Q fragments are tile-invariant: hoist
    bf16x8 qh0 = *(const bf16x8*)&Qh[wid * 16 + lr][lk * 8];
    bf16x8 ql0 = *(const bf16x8*)&Ql[wid * 16 + lr][lk * 8];
    bf16x8 qh1 = *(const bf16x8*)&Qh[wid * 16 + lr][32 + lk * 8];
    bf16x8 ql1 = *(const bf16x8*)&Ql[wid * 16 + lr][32 + lk * 8];

    f32x4 o[4];
    #pragma unroll
    for (int nf = 0; nf < 4; ++nf) { f32x4 zz = {0.f,0.f,0.f,0.f}; o[nf] = zz; }
    float lsum = 0.f;

    const int NT = 18;
    for (int tt = 0; tt < NT; ++tt) {
        // issue next tile's global loads early (T14)
        if (tt + 1 < NT) {
            const size_t ko = (size_t)((tt + 1) * 32 + skv) * 64 + sd;
            kh_r = *(const uint4*)(Khi_g + ko);
            kl_r = *(const uint4*)(Klo_g + ko);
            const size_t vo = (size_t)svd * 576 + (tt + 1) * 32 + skb;
            vh_r = *(const uint4*)(Vhi_g + vo);
            vl_r = *(const uint4*)(Vlo_g + vo);
        }

        // ---- S^T = K.Q^T, 3-pass hi/lo
        f32x4 s0 = {0.f,0.f,0.f,0.f}, s1 = {0.f,0.f,0.f,0.f};
        #pragma unroll
        for (int ks2 = 0; ks2 < 2; ++ks2) {
            const int dof = ks2 * 32 + lk * 8;
            bf16x8 qh = ks2 ? qh1 : qh0;
            bf16x8 ql = ks2 ? ql1 : ql0;
            bf16x8 k0h = *(const bf16x8*)&Kh[lr][dof];
            bf16x8 k0l = *(const bf16x8*)&Kl[lr][dof];
            bf16x8 k1h = *(const bf16x8*)&Kh[16 + lr][dof];
            bf16x8 k1l = *(const bf16x8*)&Kl[16 + lr][dof];
            s0 = __builtin_amdgcn_mfma_f32_16x16x32_bf16(k0h, qh, s0, 0, 0, 0);
            s0 = __builtin_amdgcn_mfma_f32_16x16x32_bf16(k0l, qh, s0, 0, 0, 0);
            s0 = __builtin_amdgcn_mfma_f32_16x16x32_bf16(k0h, ql, s0, 0, 0, 0);
            s1 = __builtin_amdgcn_mfma_f32_16x16x32_bf16(k1h, qh, s1, 0, 0, 0);
            s1 = __builtin_amdgcn_mfma_f32_16x16x32_bf16(k1l, qh, s1, 0, 0, 0);
            s1 = __builtin_amdgcn_mfma_f32_16x16x32_bf16(k1h, ql, s1, 0, 0, 0);
        }

        // ---- exp + pack P (lane: q=lr, kv = f*16 + lk*4 + reg)
        #pragma unroll
        for (int f = 0; f < 2; ++f) {
            f32x4 sv = f ? s1 : s0;
            float p0 = __expf(sv[0]);
            float p1 = __expf(sv[1]);
            float p2 = __expf(sv[2]);
            float p3 = __expf(sv[3]);
            lsum += (p0 + p1) + (p2 + p3);
            ushort_t h0, l0, h1, l1, h2, l2, h3, l3;
            split_hl(p0, h0, l0); split_hl(p1, h1, l1);
            split_hl(p2, h2, l2); split_hl(p3, h3, l3);
            uint2 wh, wl;
            wh.x = (unsigned int)h0 | ((unsigned int)h1 << 16);
            wh.y = (unsigned int)h2 | ((unsigned int)h3 << 16);
            wl.x = (unsigned int)l0 | ((unsigned int)l1 << 16);
            wl.y = (unsigned int)l2 | ((unsigned int)l3 << 16);
            *(uint2*)&Ph[wid][lr][f * 16 + lk * 4] = wh;
            *(uint2*)&Pl[wid][lr][f * 16 + lk * 4] = wl;
        }
        // wave-local LDS write->read ordering
        asm volatile("s_waitcnt lgkmcnt(0)" ::: "memory");
        __builtin_amdgcn_sched_barrier(0);

        // ---- O += P.V, 3-pass hi/lo (A=P [q][kv]; B=V^T [d][kv])
        {
            bf16x8 pah = *(const bf16x8*)&Ph[wid][lr][lk * 8];
            bf16x8 pal = *(const bf16x8*)&Pl[wid][lr][lk * 8];
            #pragma unroll
            for (int nf = 0; nf < 4; ++nf) {
                bf16x8 vhf = *(const bf16x8*)&Vh[nf * 16 + lr][lk * 8];
                bf16x8 vlf = *(const bf16x8*)&Vl[nf * 16 + lr][lk * 8];
                o[nf] = __builtin_amdgcn_mfma_f32_16x16x32_bf16(pah, vhf, o[nf], 0, 0, 0);
                o[nf] = __builtin_amdgcn_mfma_f32_16x16x32_bf16(pal, vhf, o[nf], 0, 0, 0);
                o[nf] = __builtin_amdgcn_mfma_f32_16x16x32_bf16(pah, vlf, o[nf], 0, 0, 0);
            }
        }

        __syncthreads();   // all waves done with this tile's K/V
        if (tt + 1 < NT) {
            *(uint4*)&Kh[skv][sd] = kh_r; *(uint4*)&Kl[skv][sd] = kl_r;
            *(uint4*)&Vh[svd][skb] = vh_r; *(uint4*)&Vl[svd][skb] = vl_r;
            __syncthreads();
        }
    }

    // ---- denominators: lane holds partial for q=lr; reduce over lk
    lsum += __shfl_xor(lsum, 16);
    lsum += __shfl_xor(lsum, 32);
    if (lk == 0) Lrow[wid][lr] = lsum;
    asm volatile("s_waitcnt lgkmcnt(0)" ::: "memory");
    __builtin_amdgcn_sched_barrier(0);

    float4 lv = *(float4*)&Lrow[wid][lk * 4];   // l for q = lk*4 + reg
    const float i0 = 1.f / lv.x, i1 = 1.f / lv.y, i2 = 1.f / lv.z, i3 = 1.f / lv.w;

    // ---- store AO in-place: lane holds O[q = lk*4+reg][d = nf*16+lr]
    const int qbase = qt * 64 + wid * 16 + lk * 4;
    #pragma unroll
    for (int nf = 0; nf < 4; ++nf) {
        float4 st;
        st.x = o[nf][0] * i0;
        st.y = o[nf][1] * i1;
        st.z = o[nf][2] * i2;
        st.w = o[nf][3] * i3;
        *(float4*)&Qs[(size_t)(nf * 16 + lr) * 576 + qbase] = st;
    }
}

// ---------------------------------------------------------------------------
// Output projection, tiled GEMM (unchanged).
// ---------------------------------------------------------------------------
__global__ __launch_bounds__(256)
void proj_out_gemm(const float* __restrict__ ao,
                   const void* __restrict__ wo, const void* __restrict__ bo,
                   void* __restrict__ out, const int* __restrict__ flag, int bt_base)
{
    const int is_f32 = flag[0];
    const int btl = blockIdx.z;
    const int bt = bt_base + btl;
    const int b = bt >> 4, t = bt & 15;
    const float* A = ao + (size_t)btl * SLABF;

    const int o0 = blockIdx.y * 64;
    const int p0 = blockIdx.x * 64;
    const int tid = threadIdx.x;
    const int tx = tid & 15;
    const int ty = tid >> 4;

    __shared__ float  As[16][68];
    __shared__ float4 Bs[16][17];

    float acc[4][4];
    #pragma unroll
    for (int r = 0; r < 4; ++r) {
        float bb = in_read(bo, (size_t)(o0 + ty * 4 + r), is_f32);
        #pragma unroll
        for (int j = 0; j < 4; ++j) acc[r][j] = bb;
    }

    const int wo_l = tid >> 2;
    const int wc_l = (tid & 3) * 4;
    const int xc_l = ty;
    const int xp_l = tx * 4;

    for (int c0 = 0; c0 < 512; c0 += 16) {
        {
            size_t wbase = (size_t)(o0 + wo_l) * 512 + (size_t)(c0 + wc_l);
            #pragma unroll
            for (int i = 0; i < 4; ++i)
                As[wc_l + i][wo_l] = in_read(wo, wbase + i, is_f32);
        }
        Bs[xc_l][tx] = *(const float4*)&A[(size_t)(c0 + xc_l) * 576 + p0 + xp_l];
        __syncthreads();
        #pragma unroll
        for (int kk = 0; kk < 16; ++kk) {
            float4 bv = Bs[kk][tx];
            #pragma unroll
            for (int r = 0; r < 4; ++r) {
                float a = As[kk][ty * 4 + r];
                acc[r][0] += a * bv.x;
                acc[r][1] += a * bv.y;
                acc[r][2] += a * bv.z;
                acc[r][3] += a * bv.w;
            }
        }
        __syncthreads();
    }

    #pragma unroll
    for (int r = 0; r < 4; ++r) {
        const int o = o0 + ty * 4 + r;
        const size_t addr = ((size_t)(b * 512 + o) * 16 + t) * 576 + p0 + tx * 4;
        if (is_f32) {
            float4 st;
            st.x = acc[r][0]; st.y = acc[r][1]; st.z = acc[r][2]; st.w = acc[r][3];
            *(float4*)((float*)out + addr) = st;
        } else {
            unsigned int lo = (unsigned int)f2bf(acc[r][0]) |
                              ((unsigned int)f2bf(acc[r][1]) << 16);
            unsigned int hi = (unsigned int)f2bf(acc[r][2]) |
                              ((unsigned int)f2bf(acc[r][3]) << 16);
            uint2 st; st.x = lo; st.y = hi;
            *(uint2*)((ushort_t*)out + addr) = st;
        }
    }
}

extern "C" void kernel_launch(void* const* d_in, const int* in_sizes, int n_in,
                              void* d_out, int out_size, void* d_ws, size_t ws_size,
                              hipStream_t stream)
{
    (void)in_sizes; (void)n_in; (void)out_size;
    const void* x   = d_in[0];
    const void* wq  = d_in[1];
    const void* bq  = d_in[2];
    const void* wk  = d_in[3];
    const void* bk  = d_in[4];
    const void* wv  = d_in[5];
    const void* bv  = d_in[6];
    const void* wo  = d_in[7];
    const void* bo  = d_in[8];
    const void* pos = d_in[9];

    int*   flag   = (int*)d_ws;
    float* bias2  = (float*)((char*)d_ws + 256);
    float* slab0  = (float*)((char*)d_ws + 256 + B2F * sizeof(float));
    const size_t head_bytes = 256 + B2F * sizeof(float);

    const size_t per_bt = (size_t)3 * SLABF * sizeof(float);
    int chunk = 1;
    if (ws_size > head_bytes + per_bt) {
        size_t c = (ws_size - head_bytes) / per_bt;
        chunk = (c > 32) ? 32 : (int)c;
    }
    if (chunk < 1) chunk = 1;

    detect_dtype<<<1, 256, 0, stream>>>((const ushort_t*)wq, flag);
    make_bias2<<<48, 256, 0, stream>>>(
        (const ushort_t*)wq, (const ushort_t*)bq,
        (const ushort_t*)wk, (const ushort_t*)bk,
        (const ushort_t*)wv, (const ushort_t*)bv,
        (const ushort_t*)pos, bias2, flag);

    for (int bt0 = 0; bt0 < 32; bt0 += chunk) {
        const int nbt = (32 - bt0 < chunk) ? (32 - bt0) : chunk;
        float* qslab = slab0;
        float* kslab = qslab + (size_t)nbt * SLABF;
        float* vslab = kslab + (size_t)nbt * SLABF;

        proj_qkv_mfma<<<dim3(9, 2, nbt * 3), 256, 0, stream>>>(
            (const ushort_t*)x, (const ushort_t*)wq, (const ushort_t*)wk,
            (const ushort_t*)wv, bias2, qslab, kslab, vslab, flag, bt0);
        proj_qkv_gemm<<<dim3(9, 8, nbt * 3), 256, 0, stream>>>(
            x, pos, wq, bq, wk, bk, wv, bv, qslab, kslab, vslab, flag, bt0);
        attn_mfma<<<dim3(nbt * 72), 256, 0, stream>>>(qslab, kslab, vslab, nbt);
        proj_out_gemm<<<dim3(9, 8, nbt), 256, 0, stream>>>(
            qslab, wo, bo, d_out, flag, bt0);
    }
}

// Round 8
// 478.651 us; speedup vs baseline: 136.9648x; 1.5091x over previous
//
#include <hip/hip_runtime.h>
#include <math.h>

typedef unsigned short ushort_t;
typedef short bf16x8 __attribute__((ext_vector_type(8)));
typedef float f32x4 __attribute__((ext_vector_type(4)));

#define SLABF (512 * 576)     /* floats per (b,t) slab; ushorts per bf16 plane */
#define APAD  40              /* LDS row pad in halves (80 B, 16B-aligned) */
#define NXF   (2 * 512 * 16 * 576)   /* elements per x plane */
#define WELEM (512 * 512)

__device__ __forceinline__ float bf2f(ushort_t u) {
    union { unsigned int i; float f; } v;
    v.i = ((unsigned int)u) << 16;
    return v.f;
}
__device__ __forceinline__ ushort_t f2bf(float f) {
    union { float f; unsigned int i; } v;
    v.f = f;
    unsigned int r = v.i + 0x7FFFu + ((v.i >> 16) & 1u);
    return (ushort_t)(r >> 16);
}
// hi/lo split: x ~= bf2f(hi) + bf2f(lo), residual ~ x*2^-17
__device__ __forceinline__ void split_hl(float x, ushort_t& hi, ushort_t& lo) {
    hi = f2bf(x);
    lo = f2bf(x - bf2f(hi));
}

// ---------------------------------------------------------------------------
// Prep 1: xsplit = hi/lo bf16 planes of (x + pos), same [b][c][t][p] layout.
// ---------------------------------------------------------------------------
__global__ __launch_bounds__(256)
void split_x(const float* __restrict__ x, const float* __restrict__ pos,
             ushort_t* __restrict__ xhi, ushort_t* __restrict__ xlo)
{
    const int n4 = NXF / 4;
    for (int i4 = blockIdx.x * 256 + threadIdx.x; i4 < n4; i4 += gridDim.x * 256) {
        float4 v = ((const float4*)x)[i4];
        const int rest = (i4 * 4) / 576;        // (b*512+c)*16 + t
        const int t = rest & 15;
        const int c = (rest >> 4) & 511;
        const float pv = pos[c * 16 + t];
        v.x += pv; v.y += pv; v.z += pv; v.w += pv;
        ushort4 h, l;
        split_hl(v.x, h.x, l.x);
        split_hl(v.y, h.y, l.y);
        split_hl(v.z, h.z, l.z);
        split_hl(v.w, h.w, l.w);
        ((ushort4*)xhi)[i4] = h;
        ((ushort4*)xlo)[i4] = l;
    }
}

// ---------------------------------------------------------------------------
// Prep 2: weight hi/lo planes. wsp layout: m in {q,k,v,o}: hi @ m*2*WELEM,
// lo @ m*2*WELEM + WELEM.
// ---------------------------------------------------------------------------
__global__ __launch_bounds__(256)
void split_w(const float* __restrict__ w0, const float* __restrict__ w1,
             const float* __restrict__ w2, const float* __restrict__ w3,
             ushort_t* __restrict__ wsp)
{
    const int m = blockIdx.y;
    const float* W = (m == 0) ? w0 : (m == 1) ? w1 : (m == 2) ? w2 : w3;
    ushort_t* hi = wsp + (size_t)m * 2 * WELEM;
    ushort_t* lo = hi + WELEM;
    const int idx = blockIdx.x * 256 + threadIdx.x;   // 0..65535
    float4 v = ((const float4*)W)[idx];
    ushort4 h, l;
    split_hl(v.x, h.x, l.x);
    split_hl(v.y, h.y, l.y);
    split_hl(v.z, h.z, l.z);
    split_hl(v.w, h.w, l.w);
    ((ushort4*)hi)[idx] = h;
    ((ushort4*)lo)[idx] = l;
}

// ---------------------------------------------------------------------------
// QKV projection, MFMA hi/lo 3-pass. Tile 128o x 64p, BK=32, 4 waves (wave
// owns 32 o). Fragment semantics = attn_mfma-verified pattern:
//   A rows [m][k], B rows [n][k] in LDS; frag = LDS[grp*16+lr][lk*8..+8];
//   D: col=lr -> n (p), row=lk*4+reg -> m (o).
// Slab outputs (match attn_mfma's expectations exactly):
//   Q fp32 [h][d][576];  K hi/lo bf16 planes [h][kv][64];
//   V hi/lo bf16 planes [h][d][576].
// ---------------------------------------------------------------------------
__global__ __launch_bounds__(256)
void proj_qkv_mfma32(const ushort_t* __restrict__ xhi, const ushort_t* __restrict__ xlo,
                     const ushort_t* __restrict__ wsp,
                     const float* __restrict__ bq, const float* __restrict__ bk,
                     const float* __restrict__ bv,
                     float* __restrict__ qs, float* __restrict__ ks, float* __restrict__ vs,
                     int bt_base)
{
    const int z = blockIdx.z;
    const int btl = z / 3;
    const int mode = z - btl * 3;
    const int bt = bt_base + btl;
    const int b = bt >> 4, t = bt & 15;

    const ushort_t* Whi = wsp + (size_t)mode * (2 * WELEM);
    const ushort_t* Wlo = Whi + WELEM;
    const float* bias = (mode == 0) ? bq : (mode == 1) ? bk : bv;
    float* out = ((mode == 0) ? qs : (mode == 1) ? ks : vs) + (size_t)btl * SLABF;

    const int o0 = blockIdx.y * 128;
    const int p0 = blockIdx.x * 64;
    const int tid = threadIdx.x;
    const int wid = tid >> 6;
    const int lane = tid & 63;
    const int lr = lane & 15;
    const int lk = lane >> 4;

    __shared__ ushort_t Wh[128 * APAD], Wl[128 * APAD];
    __shared__ ushort_t Xh[64 * APAD],  Xl[64 * APAD];

    f32x4 acc[2][4];
    #pragma unroll
    for (int i = 0; i < 2; ++i)
        #pragma unroll
        for (int j = 0; j < 4; ++j) { f32x4 zz = {0.f,0.f,0.f,0.f}; acc[i][j] = zz; }

    const int bc = tid >> 3;           // B stage: c row 0..31
    const int bp = (tid & 7) * 8;      // B stage: p offset

    for (int c0 = 0; c0 < 512; c0 += 32) {
        // A stage: 512 chunks of 16B per plane-pair; idx -> (row, 8-half off)
        #pragma unroll
        for (int k = 0; k < 2; ++k) {
            const int idx = tid + k * 256;
            const int row = idx >> 2;
            const int off = (idx & 3) * 8;
            const size_t g = (size_t)(o0 + row) * 512 + c0 + off;
            *(bf16x8*)(Wh + row * APAD + off) = *(const bf16x8*)(Whi + g);
            *(bf16x8*)(Wl + row * APAD + off) = *(const bf16x8*)(Wlo + g);
        }
        // B stage: transposed scatter [p][c]
        {
            const size_t g = ((size_t)(b * 512 + c0 + bc) * 16 + t) * 576 + p0 + bp;
            bf16x8 vh = *(const bf16x8*)(xhi + g);
            bf16x8 vl = *(const bf16x8*)(xlo + g);
            #pragma unroll
            for (int e = 0; e < 8; ++e) {
                Xh[(bp + e) * APAD + bc] = (ushort_t)vh[e];
                Xl[(bp + e) * APAD + bc] = (ushort_t)vl[e];
            }
        }
        __syncthreads();

        bf16x8 ah[2], al[2], bh[4], bl[4];
        #pragma unroll
        for (int fo = 0; fo < 2; ++fo) {
            ah[fo] = *(const bf16x8*)(Wh + (wid * 32 + fo * 16 + lr) * APAD + lk * 8);
            al[fo] = *(const bf16x8*)(Wl + (wid * 32 + fo * 16 + lr) * APAD + lk * 8);
        }
        #pragma unroll
        for (int fp = 0; fp < 4; ++fp) {
            bh[fp] = *(const bf16x8*)(Xh + (fp * 16 + lr) * APAD + lk * 8);
            bl[fp] = *(const bf16x8*)(Xl + (fp * 16 + lr) * APAD + lk * 8);
        }
        #pragma unroll
        for (int fo = 0; fo < 2; ++fo)
            #pragma unroll
            for (int fp = 0; fp < 4; ++fp) {
                acc[fo][fp] = __builtin_amdgcn_mfma_f32_16x16x32_bf16(ah[fo], bh[fp], acc[fo][fp], 0, 0, 0);
                acc[fo][fp] = __builtin_amdgcn_mfma_f32_16x16x32_bf16(al[fo], bh[fp], acc[fo][fp], 0, 0, 0);
                acc[fo][fp] = __builtin_amdgcn_mfma_f32_16x16x32_bf16(ah[fo], bl[fp], acc[fo][fp], 0, 0, 0);
            }
        __syncthreads();
    }

    if (mode == 0) {
        #pragma unroll
        for (int fo = 0; fo < 2; ++fo)
            #pragma unroll
            for (int reg = 0; reg < 4; ++reg) {
                const int o = o0 + wid * 32 + fo * 16 + lk * 4 + reg;
                const float bb = bias[o];
                #pragma unroll
                for (int fp = 0; fp < 4; ++fp)
                    out[(size_t)o * 576 + p0 + fp * 16 + lr] = acc[fo][fp][reg] + bb;
            }
    } else if (mode == 1) {
        ushort_t* khi = (ushort_t*)out;
        ushort_t* klo = khi + SLABF;
        #pragma unroll
        for (int fo = 0; fo < 2; ++fo)
            #pragma unroll
            for (int reg = 0; reg < 4; ++reg) {
                const int o = o0 + wid * 32 + fo * 16 + lk * 4 + reg;
                const float bb = bias[o];
                const size_t base = (size_t)(o >> 6) * (576 * 64) + (o & 63);
                #pragma unroll
                for (int fp = 0; fp < 4; ++fp) {
                    float v = acc[fo][fp][reg] + bb;
                    ushort_t hi, lo; split_hl(v, hi, lo);
                    const size_t off = base + (size_t)(p0 + fp * 16 + lr) * 64;
                    khi[off] = hi; klo[off] = lo;
                }
            }
    } else {
        ushort_t* vhi = (ushort_t*)out;
        ushort_t* vlo = vhi + SLABF;
        #pragma unroll
        for (int fo = 0; fo < 2; ++fo)
            #pragma unroll
            for (int reg = 0; reg < 4; ++reg) {
                const int o = o0 + wid * 32 + fo * 16 + lk * 4 + reg;
                const float bb = bias[o];
                #pragma unroll
                for (int fp = 0; fp < 4; ++fp) {
                    float v = acc[fo][fp][reg] + bb;
                    ushort_t hi, lo; split_hl(v, hi, lo);
                    const size_t off = (size_t)o * 576 + p0 + fp * 16 + lr;
                    vhi[off] = hi; vlo[off] = lo;
                }
            }
    }
}

// ---------------------------------------------------------------------------
// Attention via MFMA, hi/lo 3-pass — byte-identical to round-7 (HW-verified).
// ---------------------------------------------------------------------------
__global__ __launch_bounds__(256)
void attn_mfma(float* __restrict__ qs, const float* __restrict__ ks,
               const float* __restrict__ vs, int nbt)
{
    const int L = blockIdx.x;
    const int w9 = (L & 7) * (nbt * 9) + (L >> 3);
    const int pair = w9 / 9;
    const int qt = w9 - pair * 9;
    const int btl = pair >> 3;
    const int h = pair & 7;

    const int tid = threadIdx.x;
    const int wid = tid >> 6;
    const int lane = tid & 63;
    const int lr = lane & 15;
    const int lk = lane >> 4;

    const size_t slab = (size_t)btl * SLABF;
    float* __restrict__ Qs = qs + slab + (size_t)(h * 64) * 576;
    const ushort_t* kbase = (const ushort_t*)(ks + slab);
    const ushort_t* Khi_g = kbase + (size_t)h * (576 * 64);
    const ushort_t* Klo_g = kbase + SLABF + (size_t)h * (576 * 64);
    const ushort_t* vbase = (const ushort_t*)(vs + slab);
    const ushort_t* Vhi_g = vbase + (size_t)h * (64 * 576);
    const ushort_t* Vlo_g = vbase + SLABF + (size_t)h * (64 * 576);

    __shared__ ushort_t Kh[32][72], Kl[32][72];
    __shared__ ushort_t Vh[64][40], Vl[64][40];
    __shared__ ushort_t Qh[64][72], Ql[64][72];
    __shared__ ushort_t Ph[4][16][40], Pl[4][16][40];
    __shared__ float Lrow[4][16];

    {
        const int q = tid & 63, dd0 = (tid >> 6) * 16;
        const int qg = qt * 64 + q;
        #pragma unroll
        for (int i = 0; i < 16; ++i) {
            float v = Qs[(size_t)(dd0 + i) * 576 + qg] * 0.125f;
            ushort_t hi, lo; split_hl(v, hi, lo);
            Qh[q][dd0 + i] = hi; Ql[q][dd0 + i] = lo;
        }
    }

    const int skv = tid >> 3, sd = (tid & 7) * 8;
    const int svd = tid >> 2, skb = (tid & 3) * 8;
    uint4 kh_r, kl_r, vh_r, vl_r;

    {
        const size_t ko = (size_t)skv * 64 + sd;
        kh_r = *(const uint4*)(Khi_g + ko);
        kl_r = *(const uint4*)(Klo_g + ko);
        const size_t vo = (size_t)svd * 576 + skb;
        vh_r = *(const uint4*)(Vhi_g + vo);
        vl_r = *(const uint4*)(Vlo_g + vo);
        *(uint4*)&Kh[skv][sd] = kh_r; *(uint4*)&Kl[skv][sd] = kl_r;
        *(uint4*)&Vh[svd][skb] = vh_r; *(uint4*)&Vl[svd][skb] = vl_r;
    }
    __syncthreads();

    bf16x8 qh0 = *(const bf16x8*)&Qh[wid * 16 + lr][lk * 8];
    bf16x8 ql0 = *(const bf16x8*)&Ql[wid * 16 + lr][lk * 8];
    bf16x8 qh1 = *(const bf16x8*)&Qh[wid * 16 + lr][32 + lk * 8];
    bf16x8 ql1 = *(const bf16x8*)&Ql[wid * 16 + lr][32 + lk * 8];

    f32x4 o[4];
    #pragma unroll
    for (int nf = 0; nf < 4; ++nf) { f32x4 zz = {0.f,0.f,0.f,0.f}; o[nf] = zz; }
    float lsum = 0.f;

    const int NT = 18;
    for (int tt = 0; tt < NT; ++tt) {
        if (tt + 1 < NT) {
            const size_t ko = (size_t)((tt + 1) * 32 + skv) * 64 + sd;
            kh_r = *(const uint4*)(Khi_g + ko);
            kl_r = *(const uint4*)(Klo_g + ko);
            const size_t vo = (size_t)svd * 576 + (tt + 1) * 32 + skb;
            vh_r = *(const uint4*)(Vhi_g + vo);
            vl_r = *(const uint4*)(Vlo_g + vo);
        }

        f32x4 s0 = {0.f,0.f,0.f,0.f}, s1 = {0.f,0.f,0.f,0.f};
        #pragma unroll
        for (int ks2 = 0; ks2 < 2; ++ks2) {
            const int dof = ks2 * 32 + lk * 8;
            bf16x8 qh = ks2 ? qh1 : qh0;
            bf16x8 ql = ks2 ? ql1 : ql0;
            bf16x8 k0h = *(const bf16x8*)&Kh[lr][dof];
            bf16x8 k0l = *(const bf16x8*)&Kl[lr][dof];
            bf16x8 k1h = *(const bf16x8*)&Kh[16 + lr][dof];
            bf16x8 k1l = *(const bf16x8*)&Kl[16 + lr][dof];
            s0 = __builtin_amdgcn_mfma_f32_16x16x32_bf16(k0h, qh, s0, 0, 0, 0);
            s0 = __builtin_amdgcn_mfma_f32_16x16x32_bf16(k0l, qh, s0, 0, 0, 0);
            s0 = __builtin_amdgcn_mfma_f32_16x16x32_bf16(k0h, ql, s0, 0, 0, 0);
            s1 = __builtin_amdgcn_mfma_f32_16x16x32_bf16(k1h, qh, s1, 0, 0, 0);
            s1 = __builtin_amdgcn_mfma_f32_16x16x32_bf16(k1l, qh, s1, 0, 0, 0);
            s1 = __builtin_amdgcn_mfma_f32_16x16x32_bf16(k1h, ql, s1, 0, 0, 0);
        }

        #pragma unroll
        for (int f = 0; f < 2; ++f) {
            f32x4 sv = f ? s1 : s0;
            float p0 = __expf(sv[0]);
            float p1 = __expf(sv[1]);
            float p2 = __expf(sv[2]);
            float p3 = __expf(sv[3]);
            lsum += (p0 + p1) + (p2 + p3);
            ushort_t h0, l0, h1, l1, h2, l2, h3, l3;
            split_hl(p0, h0, l0); split_hl(p1, h1, l1);
            split_hl(p2, h2, l2); split_hl(p3, h3, l3);
            uint2 wh, wl;
            wh.x = (unsigned int)h0 | ((unsigned int)h1 << 16);
            wh.y = (unsigned int)h2 | ((unsigned int)h3 << 16);
            wl.x = (unsigned int)l0 | ((unsigned int)l1 << 16);
            wl.y = (unsigned int)l2 | ((unsigned int)l3 << 16);
            *(uint2*)&Ph[wid][lr][f * 16 + lk * 4] = wh;
            *(uint2*)&Pl[wid][lr][f * 16 + lk * 4] = wl;
        }
        asm volatile("s_waitcnt lgkmcnt(0)" ::: "memory");
        __builtin_amdgcn_sched_barrier(0);

        {
            bf16x8 pah = *(const bf16x8*)&Ph[wid][lr][lk * 8];
            bf16x8 pal = *(const bf16x8*)&Pl[wid][lr][lk * 8];
            #pragma unroll
            for (int nf = 0; nf < 4; ++nf) {
                bf16x8 vhf = *(const bf16x8*)&Vh[nf * 16 + lr][lk * 8];
                bf16x8 vlf = *(const bf16x8*)&Vl[nf * 16 + lr][lk * 8];
                o[nf] = __builtin_amdgcn_mfma_f32_16x16x32_bf16(pah, vhf, o[nf], 0, 0, 0);
                o[nf] = __builtin_amdgcn_mfma_f32_16x16x32_bf16(pal, vhf, o[nf], 0, 0, 0);
                o[nf] = __builtin_amdgcn_mfma_f32_16x16x32_bf16(pah, vlf, o[nf], 0, 0, 0);
            }
        }

        __syncthreads();
        if (tt + 1 < NT) {
            *(uint4*)&Kh[skv][sd] = kh_r; *(uint4*)&Kl[skv][sd] = kl_r;
            *(uint4*)&Vh[svd][skb] = vh_r; *(uint4*)&Vl[svd][skb] = vl_r;
            __syncthreads();
        }
    }

    lsum += __shfl_xor(lsum, 16);
    lsum += __shfl_xor(lsum, 32);
    if (lk == 0) Lrow[wid][lr] = lsum;
    asm volatile("s_waitcnt lgkmcnt(0)" ::: "memory");
    __builtin_amdgcn_sched_barrier(0);

    float4 lv = *(float4*)&Lrow[wid][lk * 4];
    const float i0 = 1.f / lv.x, i1 = 1.f / lv.y, i2 = 1.f / lv.z, i3 = 1.f / lv.w;

    const int qbase = qt * 64 + wid * 16 + lk * 4;
    #pragma unroll
    for (int nf = 0; nf < 4; ++nf) {
        float4 st;
        st.x = o[nf][0] * i0;
        st.y = o[nf][1] * i1;
        st.z = o[nf][2] * i2;
        st.w = o[nf][3] * i3;
        *(float4*)&Qs[(size_t)(nf * 16 + lr) * 576 + qbase] = st;
    }
}

// ---------------------------------------------------------------------------
// Output projection, MFMA hi/lo 3-pass. A = wo planes (pre-split); B = AO
// fp32 [c][576] split on the fly during staging. Same tile/fragment structure
// as proj_qkv_mfma32. Output fp32 to d_out.
// ---------------------------------------------------------------------------
__global__ __launch_bounds__(256)
void proj_out_mfma32(const float* __restrict__ ao, const ushort_t* __restrict__ wsp,
                     const float* __restrict__ bo, float* __restrict__ outb,
                     int bt_base)
{
    const int btl = blockIdx.z;
    const int bt = bt_base + btl;
    const int b = bt >> 4, t = bt & 15;
    const float* A0 = ao + (size_t)btl * SLABF;

    const ushort_t* Whi = wsp + (size_t)3 * (2 * WELEM);
    const ushort_t* Wlo = Whi + WELEM;

    const int o0 = blockIdx.y * 128;
    const int p0 = blockIdx.x * 64;
    const int tid = threadIdx.x;
    const int wid = tid >> 6;
    const int lane = tid & 63;
    const int lr = lane & 15;
    const int lk = lane >> 4;

    __shared__ ushort_t Wh[128 * APAD], Wl[128 * APAD];
    __shared__ ushort_t Xh[64 * APAD],  Xl[64 * APAD];

    f32x4 acc[2][4];
    #pragma unroll
    for (int i = 0; i < 2; ++i)
        #pragma unroll
        for (int j = 0; j < 4; ++j) { f32x4 zz = {0.f,0.f,0.f,0.f}; acc[i][j] = zz; }

    const int bc = tid >> 3;
    const int bp = (tid & 7) * 8;

    for (int c0 = 0; c0 < 512; c0 += 32) {
        #pragma unroll
        for (int k = 0; k < 2; ++k) {
            const int idx = tid + k * 256;
            const int row = idx >> 2;
            const int off = (idx & 3) * 8;
            const size_t g = (size_t)(o0 + row) * 512 + c0 + off;
            *(bf16x8*)(Wh + row * APAD + off) = *(const bf16x8*)(Whi + g);
            *(bf16x8*)(Wl + row * APAD + off) = *(const bf16x8*)(Wlo + g);
        }
        {
            const float* src = A0 + (size_t)(c0 + bc) * 576 + p0 + bp;
            float4 v0 = *(const float4*)(src);
            float4 v1 = *(const float4*)(src + 4);
            float vv[8] = {v0.x, v0.y, v0.z, v0.w, v1.x, v1.y, v1.z, v1.w};
            #pragma unroll
            for (int e = 0; e < 8; ++e) {
                ushort_t hi, lo; split_hl(vv[e], hi, lo);
                Xh[(bp + e) * APAD + bc] = hi;
                Xl[(bp + e) * APAD + bc] = lo;
            }
        }
        __syncthreads();

        bf16x8 ah[2], al[2], bh[4], bl[4];
        #pragma unroll
        for (int fo = 0; fo < 2; ++fo) {
            ah[fo] = *(const bf16x8*)(Wh + (wid * 32 + fo * 16 + lr) * APAD + lk * 8);
            al[fo] = *(const bf16x8*)(Wl + (wid * 32 + fo * 16 + lr) * APAD + lk * 8);
        }
        #pragma unroll
        for (int fp = 0; fp < 4; ++fp) {
            bh[fp] = *(const bf16x8*)(Xh + (fp * 16 + lr) * APAD + lk * 8);
            bl[fp] = *(const bf16x8*)(Xl + (fp * 16 + lr) * APAD + lk * 8);
        }
        #pragma unroll
        for (int fo = 0; fo < 2; ++fo)
            #pragma unroll
            for (int fp = 0; fp < 4; ++fp) {
                acc[fo][fp] = __builtin_amdgcn_mfma_f32_16x16x32_bf16(ah[fo], bh[fp], acc[fo][fp], 0, 0, 0);
                acc[fo][fp] = __builtin_amdgcn_mfma_f32_16x16x32_bf16(al[fo], bh[fp], acc[fo][fp], 0, 0, 0);
                acc[fo][fp] = __builtin_amdgcn_mfma_f32_16x16x32_bf16(ah[fo], bl[fp], acc[fo][fp], 0, 0, 0);
            }
        __syncthreads();
    }

    #pragma unroll
    for (int fo = 0; fo < 2; ++fo)
        #pragma unroll
        for (int reg = 0; reg < 4; ++reg) {
            const int o = o0 + wid * 32 + fo * 16 + lk * 4 + reg;
            const float bb = bo[o];
            const size_t base = ((size_t)(b * 512 + o) * 16 + t) * 576;
            #pragma unroll
            for (int fp = 0; fp < 4; ++fp)
                outb[base + p0 + fp * 16 + lr] = acc[fo][fp][reg] + bb;
        }
}

extern "C" void kernel_launch(void* const* d_in, const int* in_sizes, int n_in,
                              void* d_out, int out_size, void* d_ws, size_t ws_size,
                              hipStream_t stream)
{
    (void)in_sizes; (void)n_in; (void)out_size;
    const float* x   = (const float*)d_in[0];
    const float* wq  = (const float*)d_in[1];
    const float* bq  = (const float*)d_in[2];
    const float* wk  = (const float*)d_in[3];
    const float* bk  = (const float*)d_in[4];
    const float* wv  = (const float*)d_in[5];
    const float* bv  = (const float*)d_in[6];
    const float* wo  = (const float*)d_in[7];
    const float* bo  = (const float*)d_in[8];
    const float* pos = (const float*)d_in[9];

    ushort_t* xhi = (ushort_t*)d_ws;
    ushort_t* xlo = xhi + NXF;
    ushort_t* wsp = xlo + NXF;                       // 8 planes of WELEM
    float* slab0 = (float*)(wsp + 8 * WELEM);        // 40 MB head, 256B-aligned
    const size_t head_bytes = (size_t)(2 * NXF + 8 * WELEM) * 2;

    const size_t per_bt = (size_t)3 * SLABF * sizeof(float);
    int chunk = 1;
    if (ws_size > head_bytes + per_bt) {
        size_t c = (ws_size - head_bytes) / per_bt;
        chunk = (c > 32) ? 32 : (int)c;
    }
    if (chunk < 1) chunk = 1;

    split_x<<<2048, 256, 0, stream>>>(x, pos, xhi, xlo);
    split_w<<<dim3(256, 4), 256, 0, stream>>>(wq, wk, wv, wo, wsp);

    for (int bt0 = 0; bt0 < 32; bt0 += chunk) {
        const int nbt = (32 - bt0 < chunk) ? (32 - bt0) : chunk;
        float* qslab = slab0;
        float* kslab = qslab + (size_t)nbt * SLABF;
        float* vslab = kslab + (size_t)nbt * SLABF;

        proj_qkv_mfma32<<<dim3(9, 4, nbt * 3), 256, 0, stream>>>(
            xhi, xlo, wsp, bq, bk, bv, qslab, kslab, vslab, bt0);
        attn_mfma<<<dim3(nbt * 72), 256, 0, stream>>>(qslab, kslab, vslab, nbt);
        proj_out_mfma32<<<dim3(9, 4, nbt), 256, 0, stream>>>(
            qslab, wsp, bo, (float*)d_out, bt0);
    }
}

// Round 9
// 427.847 us; speedup vs baseline: 153.2287x; 1.1187x over previous
//
#include <hip/hip_runtime.h>
#include <math.h>

typedef unsigned short ushort_t;
typedef short bf16x8 __attribute__((ext_vector_type(8)));
typedef float f32x4 __attribute__((ext_vector_type(4)));

#define SLABF (512 * 576)     /* floats per (b,t) slab == ushorts per hi/lo plane pair half */
#define APAD  40              /* LDS row pad in halves (80 B, 16B-aligned) */
#define NXF   (2 * 512 * 16 * 576)   /* elements per xT plane */
#define WELEM (512 * 512)
#define HPLANE (576 * 64)     /* per-head elements of [p][64] plane */

__device__ __forceinline__ float bf2f(ushort_t u) {
    union { unsigned int i; float f; } v;
    v.i = ((unsigned int)u) << 16;
    return v.f;
}
__device__ __forceinline__ ushort_t f2bf(float f) {
    union { float f; unsigned int i; } v;
    v.f = f;
    unsigned int r = v.i + 0x7FFFu + ((v.i >> 16) & 1u);
    return (ushort_t)(r >> 16);
}
// hi/lo split: x ~= bf2f(hi) + bf2f(lo), residual ~ x*2^-17
__device__ __forceinline__ void split_hl(float x, ushort_t& hi, ushort_t& lo) {
    hi = f2bf(x);
    lo = f2bf(x - bf2f(hi));
}
// bijective XCD swizzle for N % 8 == 0 (chunked: each XCD gets N/8 consecutive)
__device__ __forceinline__ int xcd_swz(int L, int N) {
    return ((N & 7) == 0) ? ((L & 7) * (N >> 3) + (L >> 3)) : L;
}

// ---------------------------------------------------------------------------
// Prep 1: xT hi/lo planes of (x + pos), TRANSPOSED to [bt][p=576][c=512].
// LDS-tiled 64c x 64p transpose; global reads and writes both coalesced.
// grid (9 p-tiles, 8 c-tiles, 32 bt), block 256.
// ---------------------------------------------------------------------------
__global__ __launch_bounds__(256)
void split_xT(const float* __restrict__ x, const float* __restrict__ pos,
              ushort_t* __restrict__ xhi, ushort_t* __restrict__ xlo)
{
    const int bt = blockIdx.z;
    const int b = bt >> 4, t = bt & 15;
    const int pt0 = blockIdx.x * 64;
    const int ct0 = blockIdx.y * 64;
    const int tid = threadIdx.x;

    __shared__ ushort_t Th[64][72], Tl[64][72];   // [p_local][c_local]

    // load: thread owns c row (tid>>2), 16 p cols
    {
        const int cr = tid >> 2;
        const int pg = (tid & 3) * 16;
        const int c = ct0 + cr;
        const float pv = pos[c * 16 + t];
        const float* src = x + ((size_t)(b * 512 + c) * 16 + t) * 576 + pt0 + pg;
        #pragma unroll
        for (int jj = 0; jj < 4; ++jj) {
            float4 v = *(const float4*)(src + jj * 4);
            v.x += pv; v.y += pv; v.z += pv; v.w += pv;
            ushort_t h, l;
            split_hl(v.x, h, l); Th[pg + jj*4 + 0][cr] = h; Tl[pg + jj*4 + 0][cr] = l;
            split_hl(v.y, h, l); Th[pg + jj*4 + 1][cr] = h; Tl[pg + jj*4 + 1][cr] = l;
            split_hl(v.z, h, l); Th[pg + jj*4 + 2][cr] = h; Tl[pg + jj*4 + 2][cr] = l;
            split_hl(v.w, h, l); Th[pg + jj*4 + 3][cr] = h; Tl[pg + jj*4 + 3][cr] = l;
        }
    }
    __syncthreads();

    // store: thread owns p row (tid>>2), 16 c cols -> coalesced uint4 writes
    {
        const int pr = tid >> 2;
        const int cg = (tid & 3) * 16;
        const size_t obase = (size_t)bt * (576 * 512) + (size_t)(pt0 + pr) * 512 + ct0 + cg;
        #pragma unroll
        for (int m = 0; m < 2; ++m) {
            *(uint4*)(xhi + obase + m * 8) = *(const uint4*)&Th[pr][cg + m * 8];
            *(uint4*)(xlo + obase + m * 8) = *(const uint4*)&Tl[pr][cg + m * 8];
        }
    }
}

// ---------------------------------------------------------------------------
// Prep 2: weight hi/lo planes. m in {q,k,v,o}: hi @ m*2*WELEM, lo @ +WELEM.
// ---------------------------------------------------------------------------
__global__ __launch_bounds__(256)
void split_w(const float* __restrict__ w0, const float* __restrict__ w1,
             const float* __restrict__ w2, const float* __restrict__ w3,
             ushort_t* __restrict__ wsp)
{
    const int m = blockIdx.y;
    const float* W = (m == 0) ? w0 : (m == 1) ? w1 : (m == 2) ? w2 : w3;
    ushort_t* hi = wsp + (size_t)m * 2 * WELEM;
    ushort_t* lo = hi + WELEM;
    const int idx = blockIdx.x * 256 + threadIdx.x;
    float4 v = ((const float4*)W)[idx];
    ushort4 h, l;
    split_hl(v.x, h.x, l.x);
    split_hl(v.y, h.y, l.y);
    split_hl(v.z, h.z, l.z);
    split_hl(v.w, h.w, l.w);
    ((ushort4*)hi)[idx] = h;
    ((ushort4*)lo)[idx] = l;
}

// ---------------------------------------------------------------------------
// QKV projection, MFMA hi/lo 3-pass. Tile 256o x 64p, BK=32, 4 waves (wave
// owns 64 o). All LDS staging is row copies (b128, bank-uniform): A = W rows
// [o][c], B = xT rows [p][c]. Fragment/D semantics = HW-verified pattern.
// Outputs:
//   Q: hi/lo bf16 planes [h][p][64], PRE-SCALED by 0.125
//   K: hi/lo bf16 planes [h][kv][64]
//   V: hi/lo bf16 planes [h][d][576]
// 1-D grid nbt*54, XCD-chunked (bt-major per XCD).
// ---------------------------------------------------------------------------
__global__ __launch_bounds__(256)
void proj_qkv_mfma(const ushort_t* __restrict__ xhi, const ushort_t* __restrict__ xlo,
                   const ushort_t* __restrict__ wsp,
                   const float* __restrict__ bq, const float* __restrict__ bk,
                   const float* __restrict__ bv,
                   float* __restrict__ qs, float* __restrict__ ks, float* __restrict__ vs,
                   int bt_base, int nbt)
{
    const int w = xcd_swz(blockIdx.x, nbt * 54);
    const int btl = w / 54;
    int r = w - btl * 54;
    const int mode = r / 18; r -= mode * 18;
    const int ot = r / 9;
    const int pt = r - ot * 9;
    const int bt = bt_base + btl;

    const ushort_t* Whi = wsp + (size_t)mode * (2 * WELEM);
    const ushort_t* Wlo = Whi + WELEM;
    const float* bias = (mode == 0) ? bq : (mode == 1) ? bk : bv;
    float* outf = ((mode == 0) ? qs : (mode == 1) ? ks : vs) + (size_t)btl * SLABF;
    ushort_t* ohi = (ushort_t*)outf;
    ushort_t* olo = ohi + SLABF;

    const int o0 = ot * 256;
    const int p0 = pt * 64;
    const int tid = threadIdx.x;
    const int wid = tid >> 6;
    const int lane = tid & 63;
    const int lr = lane & 15;
    const int lk = lane >> 4;

    __shared__ ushort_t Wh[256 * APAD], Wl[256 * APAD];
    __shared__ ushort_t Xh[64 * APAD],  Xl[64 * APAD];

    f32x4 acc[4][4];
    #pragma unroll
    for (int i = 0; i < 4; ++i)
        #pragma unroll
        for (int j = 0; j < 4; ++j) { f32x4 zz = {0.f,0.f,0.f,0.f}; acc[i][j] = zz; }

    const int brow = tid >> 2, boff = (tid & 3) * 8;
    const ushort_t* xbh = xhi + (size_t)bt * (576 * 512);
    const ushort_t* xbl = xlo + (size_t)bt * (576 * 512);

    for (int c0 = 0; c0 < 512; c0 += 32) {
        #pragma unroll
        for (int k = 0; k < 4; ++k) {
            const int ci = tid + k * 256;
            const int row = ci >> 2, off = (ci & 3) * 8;
            const size_t g = (size_t)(o0 + row) * 512 + c0 + off;
            *(bf16x8*)(Wh + row * APAD + off) = *(const bf16x8*)(Whi + g);
            *(bf16x8*)(Wl + row * APAD + off) = *(const bf16x8*)(Wlo + g);
        }
        {
            const size_t g = (size_t)(p0 + brow) * 512 + c0 + boff;
            *(bf16x8*)(Xh + brow * APAD + boff) = *(const bf16x8*)(xbh + g);
            *(bf16x8*)(Xl + brow * APAD + boff) = *(const bf16x8*)(xbl + g);
        }
        __syncthreads();

        bf16x8 ah[4], al[4];
        #pragma unroll
        for (int fo = 0; fo < 4; ++fo) {
            ah[fo] = *(const bf16x8*)(Wh + (wid * 64 + fo * 16 + lr) * APAD + lk * 8);
            al[fo] = *(const bf16x8*)(Wl + (wid * 64 + fo * 16 + lr) * APAD + lk * 8);
        }
        #pragma unroll
        for (int fp = 0; fp < 4; ++fp) {
            bf16x8 bh = *(const bf16x8*)(Xh + (fp * 16 + lr) * APAD + lk * 8);
            bf16x8 bl = *(const bf16x8*)(Xl + (fp * 16 + lr) * APAD + lk * 8);
            #pragma unroll
            for (int fo = 0; fo < 4; ++fo) {
                acc[fo][fp] = __builtin_amdgcn_mfma_f32_16x16x32_bf16(ah[fo], bh, acc[fo][fp], 0, 0, 0);
                acc[fo][fp] = __builtin_amdgcn_mfma_f32_16x16x32_bf16(al[fo], bh, acc[fo][fp], 0, 0, 0);
                acc[fo][fp] = __builtin_amdgcn_mfma_f32_16x16x32_bf16(ah[fo], bl, acc[fo][fp], 0, 0, 0);
            }
        }
        __syncthreads();
    }

    #pragma unroll
    for (int fo = 0; fo < 4; ++fo)
        #pragma unroll
        for (int reg = 0; reg < 4; ++reg) {
            const int o = o0 + wid * 64 + fo * 16 + lk * 4 + reg;
            const float bb = bias[o];
            if (mode == 2) {
                // V: [h][d][576]
                #pragma unroll
                for (int fp = 0; fp < 4; ++fp) {
                    float v = acc[fo][fp][reg] + bb;
                    ushort_t hi, lo; split_hl(v, hi, lo);
                    const size_t off = (size_t)o * 576 + p0 + fp * 16 + lr;
                    ohi[off] = hi; olo[off] = lo;
                }
            } else {
                // Q/K: [h][p][64]; Q pre-scaled by 0.125
                const size_t base = (size_t)(o >> 6) * HPLANE + (o & 63);
                #pragma unroll
                for (int fp = 0; fp < 4; ++fp) {
                    float v = acc[fo][fp][reg] + bb;
                    if (mode == 0) v *= 0.125f;
                    ushort_t hi, lo; split_hl(v, hi, lo);
                    const size_t off = base + (size_t)(p0 + fp * 16 + lr) * 64;
                    ohi[off] = hi; olo[off] = lo;
                }
            }
        }
}

// ---------------------------------------------------------------------------
// Attention via MFMA, hi/lo 3-pass. Core loop = round-7/8 HW-verified.
// Changes: Q staged from pre-split/pre-scaled planes [h][p][64] (uint4 copies);
// AO written back IN PLACE into the same Q-plane cells as hi/lo bf16 (race-
// free: block reads exactly the (h, q-rows) it later writes).
// ---------------------------------------------------------------------------
__global__ __launch_bounds__(256)
void attn_mfma(float* __restrict__ qs, const float* __restrict__ ks,
               const float* __restrict__ vs, int nbt)
{
    const int w9 = xcd_swz(blockIdx.x, nbt * 72);
    const int pair = w9 / 9;
    const int qt = w9 - pair * 9;
    const int btl = pair >> 3;
    const int h = pair & 7;

    const int tid = threadIdx.x;
    const int wid = tid >> 6;
    const int lane = tid & 63;
    const int lr = lane & 15;
    const int lk = lane >> 4;

    const size_t slab = (size_t)btl * SLABF;
    ushort_t* Qhi_g = (ushort_t*)(qs + slab) + (size_t)h * HPLANE;        // [p][64]
    ushort_t* Qlo_g = (ushort_t*)(qs + slab) + SLABF + (size_t)h * HPLANE;
    const ushort_t* kbase = (const ushort_t*)(ks + slab);
    const ushort_t* Khi_g = kbase + (size_t)h * HPLANE;                   // [kv][64]
    const ushort_t* Klo_g = kbase + SLABF + (size_t)h * HPLANE;
    const ushort_t* vbase = (const ushort_t*)(vs + slab);
    const ushort_t* Vhi_g = vbase + (size_t)h * HPLANE;                   // [d][576]
    const ushort_t* Vlo_g = vbase + SLABF + (size_t)h * HPLANE;

    __shared__ ushort_t Kh[32][72], Kl[32][72];
    __shared__ ushort_t Vh[64][40], Vl[64][40];
    __shared__ ushort_t Qh[64][72], Ql[64][72];
    __shared__ ushort_t Ph[4][16][40], Pl[4][16][40];
    __shared__ float Lrow[4][16];

    // ---- stage Q from planes (already scaled+split): clean uint4 copies
    #pragma unroll
    for (int k = 0; k < 2; ++k) {
        const int ci = tid + k * 256;
        const int row = ci >> 3;
        const int off = (ci & 7) * 8;
        const size_t g = (size_t)(qt * 64 + row) * 64 + off;
        *(uint4*)&Qh[row][off] = *(const uint4*)(Qhi_g + g);
        *(uint4*)&Ql[row][off] = *(const uint4*)(Qlo_g + g);
    }

    const int skv = tid >> 3, sd = (tid & 7) * 8;
    const int svd = tid >> 2, skb = (tid & 3) * 8;
    uint4 kh_r, kl_r, vh_r, vl_r;

    {
        const size_t ko = (size_t)skv * 64 + sd;
        kh_r = *(const uint4*)(Khi_g + ko);
        kl_r = *(const uint4*)(Klo_g + ko);
        const size_t vo = (size_t)svd * 576 + skb;
        vh_r = *(const uint4*)(Vhi_g + vo);
        vl_r = *(const uint4*)(Vlo_g + vo);
        *(uint4*)&Kh[skv][sd] = kh_r; *(uint4*)&Kl[skv][sd] = kl_r;
        *(uint4*)&Vh[svd][skb] = vh_r; *(uint4*)&Vl[svd][skb] = vl_r;
    }
    __syncthreads();

    bf16x8 qh0 = *(const bf16x8*)&Qh[wid * 16 + lr][lk * 8];
    bf16x8 ql0 = *(const bf16x8*)&Ql[wid * 16 + lr][lk * 8];
    bf16x8 qh1 = *(const bf16x8*)&Qh[wid * 16 + lr][32 + lk * 8];
    bf16x8 ql1 = *(const bf16x8*)&Ql[wid * 16 + lr][32 + lk * 8];

    f32x4 o[4];
    #pragma unroll
    for (int nf = 0; nf < 4; ++nf) { f32x4 zz = {0.f,0.f,0.f,0.f}; o[nf] = zz; }
    float lsum = 0.f;

    const int NT = 18;
    for (int tt = 0; tt < NT; ++tt) {
        if (tt + 1 < NT) {
            const size_t ko = (size_t)((tt + 1) * 32 + skv) * 64 + sd;
            kh_r = *(const uint4*)(Khi_g + ko);
            kl_r = *(const uint4*)(Klo_g + ko);
            const size_t vo = (size_t)svd * 576 + (tt + 1) * 32 + skb;
            vh_r = *(const uint4*)(Vhi_g + vo);
            vl_r = *(const uint4*)(Vlo_g + vo);
        }

        f32x4 s0 = {0.f,0.f,0.f,0.f}, s1 = {0.f,0.f,0.f,0.f};
        #pragma unroll
        for (int ks2 = 0; ks2 < 2; ++ks2) {
            const int dof = ks2 * 32 + lk * 8;
            bf16x8 qh = ks2 ? qh1 : qh0;
            bf16x8 ql = ks2 ? ql1 : ql0;
            bf16x8 k0h = *(const bf16x8*)&Kh[lr][dof];
            bf16x8 k0l = *(const bf16x8*)&Kl[lr][dof];
            bf16x8 k1h = *(const bf16x8*)&Kh[16 + lr][dof];
            bf16x8 k1l = *(const bf16x8*)&Kl[16 + lr][dof];
            s0 = __builtin_amdgcn_mfma_f32_16x16x32_bf16(k0h, qh, s0, 0, 0, 0);
            s0 = __builtin_amdgcn_mfma_f32_16x16x32_bf16(k0l, qh, s0, 0, 0, 0);
            s0 = __builtin_amdgcn_mfma_f32_16x16x32_bf16(k0h, ql, s0, 0, 0, 0);
            s1 = __builtin_amdgcn_mfma_f32_16x16x32_bf16(k1h, qh, s1, 0, 0, 0);
            s1 = __builtin_amdgcn_mfma_f32_16x16x32_bf16(k1l, qh, s1, 0, 0, 0);
            s1 = __builtin_amdgcn_mfma_f32_16x16x32_bf16(k1h, ql, s1, 0, 0, 0);
        }

        #pragma unroll
        for (int f = 0; f < 2; ++f) {
            f32x4 sv = f ? s1 : s0;
            float p0 = __expf(sv[0]);
            float p1 = __expf(sv[1]);
            float p2 = __expf(sv[2]);
            float p3 = __expf(sv[3]);
            lsum += (p0 + p1) + (p2 + p3);
            ushort_t h0, l0, h1, l1, h2, l2, h3, l3;
            split_hl(p0, h0, l0); split_hl(p1, h1, l1);
            split_hl(p2, h2, l2); split_hl(p3, h3, l3);
            uint2 wh, wl;
            wh.x = (unsigned int)h0 | ((unsigned int)h1 << 16);
            wh.y = (unsigned int)h2 | ((unsigned int)h3 << 16);
            wl.x = (unsigned int)l0 | ((unsigned int)l1 << 16);
            wl.y = (unsigned int)l2 | ((unsigned int)l3 << 16);
            *(uint2*)&Ph[wid][lr][f * 16 + lk * 4] = wh;
            *(uint2*)&Pl[wid][lr][f * 16 + lk * 4] = wl;
        }
        asm volatile("s_waitcnt lgkmcnt(0)" ::: "memory");
        __builtin_amdgcn_sched_barrier(0);

        {
            bf16x8 pah = *(const bf16x8*)&Ph[wid][lr][lk * 8];
            bf16x8 pal = *(const bf16x8*)&Pl[wid][lr][lk * 8];
            #pragma unroll
            for (int nf = 0; nf < 4; ++nf) {
                bf16x8 vhf = *(const bf16x8*)&Vh[nf * 16 + lr][lk * 8];
                bf16x8 vlf = *(const bf16x8*)&Vl[nf * 16 + lr][lk * 8];
                o[nf] = __builtin_amdgcn_mfma_f32_16x16x32_bf16(pah, vhf, o[nf], 0, 0, 0);
                o[nf] = __builtin_amdgcn_mfma_f32_16x16x32_bf16(pal, vhf, o[nf], 0, 0, 0);
                o[nf] = __builtin_amdgcn_mfma_f32_16x16x32_bf16(pah, vlf, o[nf], 0, 0, 0);
            }
        }

        __syncthreads();
        if (tt + 1 < NT) {
            *(uint4*)&Kh[skv][sd] = kh_r; *(uint4*)&Kl[skv][sd] = kl_r;
            *(uint4*)&Vh[svd][skb] = vh_r; *(uint4*)&Vl[svd][skb] = vl_r;
            __syncthreads();
        }
    }

    lsum += __shfl_xor(lsum, 16);
    lsum += __shfl_xor(lsum, 32);
    if (lk == 0) Lrow[wid][lr] = lsum;
    asm volatile("s_waitcnt lgkmcnt(0)" ::: "memory");
    __builtin_amdgcn_sched_barrier(0);

    float4 lv = *(float4*)&Lrow[wid][lk * 4];
    const float inv[4] = {1.f / lv.x, 1.f / lv.y, 1.f / lv.z, 1.f / lv.w};

    // ---- AO in place into Q planes [h][p][64]: lane holds O[q=qrow+reg][d=nf*16+lr]
    const int qrow = qt * 64 + wid * 16 + lk * 4;
    #pragma unroll
    for (int nf = 0; nf < 4; ++nf)
        #pragma unroll
        for (int reg = 0; reg < 4; ++reg) {
            float v = o[nf][reg] * inv[reg];
            ushort_t hi, lo; split_hl(v, hi, lo);
            const size_t off = (size_t)(qrow + reg) * 64 + nf * 16 + lr;
            Qhi_g[off] = hi; Qlo_g[off] = lo;
        }
}

// ---------------------------------------------------------------------------
// Output projection, MFMA hi/lo 3-pass. Tile 256o x 64p. A = wo planes; B =
// AO planes [h][p][64] (pre-split by attn) — clean row copies, no conflicts.
// 1-D grid nbt*18, XCD-chunked. Output fp32 to d_out.
// ---------------------------------------------------------------------------
__global__ __launch_bounds__(256)
void proj_out_mfma(const float* __restrict__ ao, const ushort_t* __restrict__ wsp,
                   const float* __restrict__ bo, float* __restrict__ outb,
                   int bt_base, int nbt)
{
    const int w = xcd_swz(blockIdx.x, nbt * 18);
    const int btl = w / 18;
    int r = w - btl * 18;
    const int ot = r / 9;
    const int pt = r - ot * 9;
    const int bt = bt_base + btl;
    const int b = bt >> 4, t = bt & 15;

    const ushort_t* AOhi = (const ushort_t*)(ao + (size_t)btl * SLABF);
    const ushort_t* AOlo = AOhi + SLABF;
    const ushort_t* Whi = wsp + (size_t)3 * (2 * WELEM);
    const ushort_t* Wlo = Whi + WELEM;

    const int o0 = ot * 256;
    const int p0 = pt * 64;
    const int tid = threadIdx.x;
    const int wid = tid >> 6;
    const int lane = tid & 63;
    const int lr = lane & 15;
    const int lk = lane >> 4;

    __shared__ ushort_t Wh[256 * APAD], Wl[256 * APAD];
    __shared__ ushort_t Xh[64 * APAD],  Xl[64 * APAD];

    f32x4 acc[4][4];
    #pragma unroll
    for (int i = 0; i < 4; ++i)
        #pragma unroll
        for (int j = 0; j < 4; ++j) { f32x4 zz = {0.f,0.f,0.f,0.f}; acc[i][j] = zz; }

    const int brow = tid >> 2, boff = (tid & 3) * 8;

    for (int c0 = 0; c0 < 512; c0 += 32) {
        #pragma unroll
        for (int k = 0; k < 4; ++k) {
            const int ci = tid + k * 256;
            const int row = ci >> 2, off = (ci & 3) * 8;
            const size_t g = (size_t)(o0 + row) * 512 + c0 + off;
            *(bf16x8*)(Wh + row * APAD + off) = *(const bf16x8*)(Whi + g);
            *(bf16x8*)(Wl + row * APAD + off) = *(const bf16x8*)(Wlo + g);
        }
        {
            // AO row for c-range [c0, c0+32): head h=c0>>6, d0 = c0&63
            const size_t g = (size_t)(c0 >> 6) * HPLANE
                           + (size_t)(p0 + brow) * 64 + (c0 & 63) + boff;
            *(bf16x8*)(Xh + brow * APAD + boff) = *(const bf16x8*)(AOhi + g);
            *(bf16x8*)(Xl + brow * APAD + boff) = *(const bf16x8*)(AOlo + g);
        }
        __syncthreads();

        bf16x8 ah[4], al[4];
        #pragma unroll
        for (int fo = 0; fo < 4; ++fo) {
            ah[fo] = *(const bf16x8*)(Wh + (wid * 64 + fo * 16 + lr) * APAD + lk * 8);
            al[fo] = *(const bf16x8*)(Wl + (wid * 64 + fo * 16 + lr) * APAD + lk * 8);
        }
        #pragma unroll
        for (int fp = 0; fp < 4; ++fp) {
            bf16x8 bh = *(const bf16x8*)(Xh + (fp * 16 + lr) * APAD + lk * 8);
            bf16x8 bl = *(const bf16x8*)(Xl + (fp * 16 + lr) * APAD + lk * 8);
            #pragma unroll
            for (int fo = 0; fo < 4; ++fo) {
                acc[fo][fp] = __builtin_amdgcn_mfma_f32_16x16x32_bf16(ah[fo], bh, acc[fo][fp], 0, 0, 0);
                acc[fo][fp] = __builtin_amdgcn_mfma_f32_16x16x32_bf16(al[fo], bh, acc[fo][fp], 0, 0, 0);
                acc[fo][fp] = __builtin_amdgcn_mfma_f32_16x16x32_bf16(ah[fo], bl, acc[fo][fp], 0, 0, 0);
            }
        }
        __syncthreads();
    }

    #pragma unroll
    for (int fo = 0; fo < 4; ++fo)
        #pragma unroll
        for (int reg = 0; reg < 4; ++reg) {
            const int o = o0 + wid * 64 + fo * 16 + lk * 4 + reg;
            const float bb = bo[o];
            const size_t base = ((size_t)(b * 512 + o) * 16 + t) * 576;
            #pragma unroll
            for (int fp = 0; fp < 4; ++fp)
                outb[base + p0 + fp * 16 + lr] = acc[fo][fp][reg] + bb;
        }
}

extern "C" void kernel_launch(void* const* d_in, const int* in_sizes, int n_in,
                              void* d_out, int out_size, void* d_ws, size_t ws_size,
                              hipStream_t stream)
{
    (void)in_sizes; (void)n_in; (void)out_size;
    const float* x   = (const float*)d_in[0];
    const float* wq  = (const float*)d_in[1];
    const float* bq  = (const float*)d_in[2];
    const float* wk  = (const float*)d_in[3];
    const float* bk  = (const float*)d_in[4];
    const float* wv  = (const float*)d_in[5];
    const float* bv  = (const float*)d_in[6];
    const float* wo  = (const float*)d_in[7];
    const float* bo  = (const float*)d_in[8];
    const float* pos = (const float*)d_in[9];

    ushort_t* xhi = (ushort_t*)d_ws;
    ushort_t* xlo = xhi + NXF;
    ushort_t* wsp = xlo + NXF;                       // 8 planes of WELEM
    float* slab0 = (float*)(wsp + 8 * WELEM);
    const size_t head_bytes = (size_t)(2 * NXF + 8 * WELEM) * 2;

    const size_t per_bt = (size_t)3 * SLABF * sizeof(float);
    int chunk = 1;
    if (ws_size > head_bytes + per_bt) {
        size_t c = (ws_size - head_bytes) / per_bt;
        chunk = (c > 32) ? 32 : (int)c;
    }
    if (chunk < 1) chunk = 1;

    split_xT<<<dim3(9, 8, 32), 256, 0, stream>>>(x, pos, xhi, xlo);
    split_w<<<dim3(256, 4), 256, 0, stream>>>(wq, wk, wv, wo, wsp);

    for (int bt0 = 0; bt0 < 32; bt0 += chunk) {
        const int nbt = (32 - bt0 < chunk) ? (32 - bt0) : chunk;
        float* qslab = slab0;
        float* kslab = qslab + (size_t)nbt * SLABF;
        float* vslab = kslab + (size_t)nbt * SLABF;

        proj_qkv_mfma<<<dim3(nbt * 54), 256, 0, stream>>>(
            xhi, xlo, wsp, bq, bk, bv, qslab, kslab, vslab, bt0, nbt);
        attn_mfma<<<dim3(nbt * 72), 256, 0, stream>>>(qslab, kslab, vslab, nbt);
        proj_out_mfma<<<dim3(nbt * 18), 256, 0, stream>>>(
            qslab, wsp, bo, (float*)d_out, bt0, nbt);
    }
}